// Round 8
// baseline (364.096 us; speedup 1.0000x reference)
//
#include <hip/hip_runtime.h>

#define N_NODES 10000
#define N_EDGES 320000
#define N_PAIRS 1000000
#define NBUCK 8
#define DBW 1250            // d-bucket width (N_NODES / 8)
#define SBW 1250            // s-bucket width for coarse stage
#define SMAX 10240          // run-index stride per bucket (40 x 256: alloc chunks never straddle buckets)
#define NRUNS2 (NBUCK * SMAX)     // 81920
#define BSEG 160000         // per-bucket parr segment (expected ~142.5K padded, 5-sigma safe)
#define BCAP 17408          // coarse-bucket capacity (expected 15625, sigma~124)
#define GXM 157             // (N_NODES + 63) / 64
#define FILL16 720000       // (NBUCK*BSEG*8 + NBUCK*(BSEG/4)*4) / 16 -- parr+srun 0xFF fill, uint4 units

typedef unsigned short ushort_t;
typedef __attribute__((ext_vector_type(8))) short short8;
typedef __attribute__((ext_vector_type(4))) float floatx4;
typedef _Float16 half2_t __attribute__((ext_vector_type(2)));

__device__ inline float blo(unsigned int u) { return __uint_as_float(u << 16); }
__device__ inline float bhi(unsigned int u) { return __uint_as_float(u & 0xffff0000u); }
__device__ inline ushort_t f2bf(float f) {
    unsigned int u = __float_as_uint(f);
    unsigned int r = (u + 0x7fffu + ((u >> 16) & 1u)) >> 16;
    return (ushort_t)r;
}
__device__ inline float bf2f(ushort_t b) { return __uint_as_float(((unsigned int)b) << 16); }
__device__ inline void stout(float* p, float v) { *p = v; }
__device__ inline void stout(ushort_t* p, float v) { *p = f2bf(v); }
__device__ inline void stout(_Float16* p, float v) { *p = (_Float16)v; }

// ================= device bodies =================

// coarse 64-bucket (d/1250, s/1250) scatter, LDS-aggregated cursors; virtual grid 1024.
__device__ void dev_pstage(int bid, const int* __restrict__ el, int* __restrict__ gcur,
                           int2* __restrict__ stage) {
    __shared__ int lcnt[64], lbase[64], lcur[64];
    int t = threadIdx.x;
    if (t < 64) { lcnt[t] = 0; lcur[t] = 0; }
    __syncthreads();
    const int STR = 1024 * 256;
    int i0 = bid * 256 + t;
    int sx[4], dx[4];
#pragma unroll
    for (int k = 0; k < 4; k++) {
        int i = i0 + k * STR;
        if (i < N_PAIRS) {
            int s = el[i], d = el[N_PAIRS + i];
            sx[k] = s; dx[k] = d;
            atomicAdd(&lcnt[(d / DBW) * 8 + s / SBW], 1);
        }
    }
    __syncthreads();
    if (t < 64 && lcnt[t] > 0) lbase[t] = atomicAdd(&gcur[t * 16], lcnt[t]);
    __syncthreads();
#pragma unroll
    for (int k = 0; k < 4; k++) {
        int i = i0 + k * STR;
        if (i < N_PAIRS) {
            int s = sx[k], d = dx[k];
            int c = (d / DBW) * 8 + s / SBW;
            int r = atomicAdd(&lcur[c], 1);
            stage[(size_t)c * BCAP + lbase[c] + r] = make_int2(s | (d << 14), i);
        }
    }
}

__device__ void dev_hist(int bid, const int* __restrict__ ei, int* __restrict__ cnt) {
    int e = bid * 256 + threadIdx.x;
    if (e < N_EDGES) atomicAdd(&cnt[ei[N_EDGES + e]], 1);
}

__device__ void dev_xsplit(int bid, const float* __restrict__ x, ushort_t* __restrict__ xh) {
    int i = bid * 256 + threadIdx.x;
    if (i >= N_NODES * 256 / 4) return;
    float4 f = ((const float4*)x)[i];
    union { uint2 v; ushort_t u[4]; } H;
    H.u[0] = f2bf(f.x); H.u[1] = f2bf(f.y); H.u[2] = f2bf(f.z); H.u[3] = f2bf(f.w);
    ((uint2*)xh)[i] = H.v;
}

__device__ void dev_fill(int bid, uint4* __restrict__ dst) {
    int i = bid * 256 + threadIdx.x;
    if (i < FILL16) dst[i] = make_uint4(~0u, ~0u, ~0u, ~0u);
}

__device__ void dev_wsplit(int bx, int by, int bz,
                           const float* Wr1, const float* Wo1, const float* Wr2, const float* Wo2,
                           const float* Wr3, const float* Wo3, const float* Wd1,
                           ushort_t* r1h, ushort_t* o1h, ushort_t* r2h, ushort_t* o2h,
                           ushort_t* r3h, ushort_t* o3h, ushort_t* dah, ushort_t* dbh) {
    const float* src; ushort_t* dh; int K, NC;
    switch (bz) {
        case 0: src = Wr1; dh = r1h; K = 256; NC = 256; break;
        case 1: src = Wo1; dh = o1h; K = 256; NC = 256; break;
        case 2: src = Wr2; dh = r2h; K = 256; NC = 128; break;
        case 3: src = Wo2; dh = o2h; K = 256; NC = 128; break;
        case 4: src = Wr3; dh = r3h; K = 128; NC = 128; break;
        case 5: src = Wo3; dh = o3h; K = 128; NC = 128; break;
        case 6: src = Wd1;             dh = dah; K = 128; NC = 256; break;
        default: src = Wd1 + 128 * 256; dh = dbh; K = 128; NC = 256; break;
    }
    int tk = bx * 32, tn = by * 32;
    if (tk >= K || tn >= NC) return;
    __shared__ float tile[32][33];
    int tx = threadIdx.x & 31, ty0 = threadIdx.x >> 5;
#pragma unroll
    for (int r = 0; r < 4; r++) {
        int k = tk + ty0 + r * 8;
        tile[ty0 + r * 8][tx] = src[(size_t)k * NC + tn + tx];
    }
    __syncthreads();
#pragma unroll
    for (int r = 0; r < 4; r++) {
        int n = tn + ty0 + r * 8;
        dh[(size_t)n * K + tk + tx] = f2bf(tile[tx][ty0 + r * 8]);
    }
}

// block-local scan + one global atomicAdd per block (edges CSR alloc)
__device__ void dev_ealloc(int bid, const int* __restrict__ cnt,
                           int* __restrict__ base_, int* __restrict__ end_,
                           int* __restrict__ cur_, int* __restrict__ tot) {
    __shared__ int part[256];
    __shared__ int bbase;
    int t = threadIdx.x;
    int r = bid * 256 + t;
    int len = (r < N_NODES) ? cnt[r] : 0;
    part[t] = len;
    __syncthreads();
    for (int d = 1; d < 256; d <<= 1) {
        int v = (t >= d) ? part[t - d] : 0;
        __syncthreads();
        part[t] += v;
        __syncthreads();
    }
    if (t == 255) bbase = atomicAdd(tot, part[255]);
    __syncthreads();
    int excl = (t == 0) ? 0 : part[t - 1];
    if (r < N_NODES) {
        int b = bbase + excl;
        base_[r] = b;
        cur_[r] = b;
        end_[r] = b + len;
    }
}

__device__ void dev_phist2(int vb, const int2* __restrict__ stage, const int* __restrict__ gcur,
                           int* __restrict__ pcnt) {
    int c = vb & 63;
    int j = vb >> 6, J = 32;
    int x = c >> 3;
    int len = gcur[c * 16];
    int lo = (int)((long)len * j / J), hi = (int)((long)len * (j + 1) / J);
    const int2* sb = stage + (size_t)c * BCAP;
    for (int i = lo + threadIdx.x; i < hi; i += 256) {
        int s = sb[i].x & 16383;
        atomicAdd(&pcnt[x * SMAX + s], 1);
    }
}

__device__ void dev_scatter(int bid, const int* __restrict__ ei, const float* __restrict__ ew,
                            int* __restrict__ ecur, int2* __restrict__ csr) {
    int e = bid * 256 + threadIdx.x;
    if (e < N_EDGES) {
        int d = ei[N_EDGES + e];
        int pos = atomicAdd(&ecur[d], 1);
        csr[pos] = make_int2(ei[e], __float_as_int(ew[e]));
    }
}

// per-BUCKET bump alloc (runs x4-padded) + srun group table
__device__ void dev_palloc2(int bid, const int* __restrict__ pcnt,
                            int* __restrict__ pcur, int* __restrict__ srun,
                            int* __restrict__ ptot) {
    __shared__ int part[256];
    __shared__ int bbase;
    int t = threadIdx.x;
    int r = bid * 256 + t;
    int x = bid / (SMAX / 256);
    int s = r - x * SMAX;
    int len = pcnt[r];
    int pad = (len + 3) & ~3;
    part[t] = pad;
    __syncthreads();
    for (int d = 1; d < 256; d <<= 1) {
        int v = (t >= d) ? part[t - d] : 0;
        __syncthreads();
        part[t] += v;
        __syncthreads();
    }
    if (t == 255) bbase = atomicAdd(&ptot[x * 16], part[255]);
    __syncthreads();
    int excl = (t == 0) ? 0 : part[t - 1];
    int b = bbase + excl;
    pcur[r] = x * BSEG + b;
    int aoff = s << 9;
    int* sg = srun + x * (BSEG / 4);
#pragma clang loop unroll(disable)
    for (int gq = b >> 2, ge = (b + pad) >> 2; gq < ge; ++gq) sg[gq] = aoff;
}

__device__ void dev_pscat3(int vb, const int2* __restrict__ stage, const int* __restrict__ gcur,
                           int* __restrict__ pcur, int2* __restrict__ parr) {
    int c = vb & 63;
    int j = vb >> 6, J = 32;
    int x = c >> 3;
    int len = gcur[c * 16];
    int lo = (int)((long)len * j / J), hi = (int)((long)len * (j + 1) / J);
    const int2* sb = stage + (size_t)c * BCAP;
    for (int i = lo + threadIdx.x; i < hi; i += 256) {
        int2 p = sb[i];
        int s = p.x & 16383, d = p.x >> 14;
        int pos = atomicAdd(&pcur[x * SMAX + s], 1);
        parr[pos] = make_int2(d << 9, p.y);
    }
}

// ---------------- MFMA dual-GEMM body ----------------
template <bool ALO, typename T1, typename T2>
__device__ void dev_gemm(int bx, int by,
                         const ushort_t* __restrict__ Ahi, const ushort_t* __restrict__ Alo,
                         const ushort_t* __restrict__ W1hi, const ushort_t* __restrict__ W2hi,
                         const float* __restrict__ bias1,
                         T1* __restrict__ out1, T2* __restrict__ out2,
                         int M, int K, int NC) {
    __shared__ ushort_t sAh[64][32], sAl[ALO ? 64 : 1][32];
    __shared__ ushort_t s1h[64][32], s2h[64][32];

    int tid = threadIdx.x;
    int lane = tid & 63, wid = tid >> 6;
    int wm = wid >> 1, wn = wid & 1;
    int l15 = lane & 15, quad = lane >> 4;
    int row0 = bx * 64, col0 = by * 64;

    int srow = tid >> 2, schunk = (tid & 3) * 8;
    int arow = row0 + srow; if (arow > M - 1) arow = M - 1;
    const ushort_t* gAh = Ahi + (size_t)arow * K + schunk;
    const ushort_t* gAl = Alo + (size_t)arow * K + schunk;
    int wrow = col0 + srow;
    const ushort_t* g1h = W1hi + (size_t)wrow * K + schunk;
    const ushort_t* g2h = W2hi + (size_t)wrow * K + schunk;

    floatx4 acc1[2][2] = {}, acc2[2][2] = {};

    for (int kk = 0; kk < K; kk += 32) {
        *(short8*)&sAh[srow][schunk] = *(const short8*)(gAh + kk);
        if (ALO) *(short8*)&sAl[srow][schunk] = *(const short8*)(gAl + kk);
        *(short8*)&s1h[srow][schunk] = *(const short8*)(g1h + kk);
        *(short8*)&s2h[srow][schunk] = *(const short8*)(g2h + kk);
        __syncthreads();

        short8 ah[2], al[2], b1h[2], b2h[2];
#pragma unroll
        for (int t = 0; t < 2; t++) {
            int ar = wm * 32 + t * 16 + l15;
            ah[t] = *(const short8*)&sAh[ar][quad * 8];
            if (ALO) al[t] = *(const short8*)&sAl[ar][quad * 8];
            int bc = wn * 32 + t * 16 + l15;
            b1h[t] = *(const short8*)&s1h[bc][quad * 8];
            b2h[t] = *(const short8*)&s2h[bc][quad * 8];
        }
#pragma unroll
        for (int tm = 0; tm < 2; tm++)
#pragma unroll
            for (int tn = 0; tn < 2; tn++) {
                acc1[tm][tn] = __builtin_amdgcn_mfma_f32_16x16x32_bf16(ah[tm], b1h[tn], acc1[tm][tn], 0, 0, 0);
                acc2[tm][tn] = __builtin_amdgcn_mfma_f32_16x16x32_bf16(ah[tm], b2h[tn], acc2[tm][tn], 0, 0, 0);
                if (ALO) {
                    acc1[tm][tn] = __builtin_amdgcn_mfma_f32_16x16x32_bf16(al[tm], b1h[tn], acc1[tm][tn], 0, 0, 0);
                    acc2[tm][tn] = __builtin_amdgcn_mfma_f32_16x16x32_bf16(al[tm], b2h[tn], acc2[tm][tn], 0, 0, 0);
                }
            }
        __syncthreads();
    }

    // C/D layout: col = lane&15, row = quad*4 + reg
#pragma unroll
    for (int tm = 0; tm < 2; tm++) {
#pragma unroll
        for (int tn = 0; tn < 2; tn++) {
            int gc = col0 + wn * 32 + tn * 16 + l15;
            float bv = bias1 ? bias1[gc] : 0.f;
#pragma unroll
            for (int reg = 0; reg < 4; reg++) {
                int gr = row0 + wm * 32 + tm * 16 + quad * 4 + reg;
                if (gr >= M) continue;
                stout(&out1[(size_t)gr * NC + gc], acc1[tm][tn][reg] + bv);
                stout(&out2[(size_t)gr * NC + gc], acc2[tm][tn][reg]);
            }
        }
    }
}

// ================= fused dispatches =================

// K1: [pstage 1024 | hist 1250 | xsplit 2500 | wsplit 512 | parr/srun 0xFF fill 2813] = 8099 blocks
__global__ __launch_bounds__(256) void k_fuse1(
    const int* __restrict__ el, int* __restrict__ gcur, int2* __restrict__ stage,
    const int* __restrict__ ei, int* __restrict__ cnt,
    const float* __restrict__ x, ushort_t* __restrict__ ash,
    uint4* __restrict__ fillbase,
    const float* Wr1, const float* Wo1, const float* Wr2, const float* Wo2,
    const float* Wr3, const float* Wo3, const float* Wd1,
    ushort_t* r1h, ushort_t* o1h, ushort_t* r2h, ushort_t* o2h,
    ushort_t* r3h, ushort_t* o3h, ushort_t* dah, ushort_t* dbh) {
    int b = blockIdx.x;
    if (b < 1024) { dev_pstage(b, el, gcur, stage); return; }
    b -= 1024;
    if (b < 1250) { dev_hist(b, ei, cnt); return; }
    b -= 1250;
    if (b < 2500) { dev_xsplit(b, x, ash); return; }
    b -= 2500;
    if (b < 512) {
        dev_wsplit(b & 7, (b >> 3) & 7, b >> 6, Wr1, Wo1, Wr2, Wo2, Wr3, Wo3, Wd1,
                   r1h, o1h, r2h, o2h, r3h, o3h, dah, dbh);
        return;
    }
    dev_fill(b - 512, fillbase);
}

// K2: [edge alloc 40 | phist2 2048] = 2088 blocks
__global__ __launch_bounds__(256) void k_fuse2(
    const int* __restrict__ cnt, int* __restrict__ ebase, int* __restrict__ eend,
    int* __restrict__ ecur, int* __restrict__ etot,
    const int2* __restrict__ stage, const int* __restrict__ gcur, int* __restrict__ pcnt) {
    int b = blockIdx.x;
    if (b < 40) { dev_ealloc(b, cnt, ebase, eend, ecur, etot); return; }
    dev_phist2(b - 40, stage, gcur, pcnt);
}

// K3: [edge scatter 1250 | palloc2 320] = 1570 blocks
__global__ __launch_bounds__(256) void k_fuse3(
    const int* __restrict__ ei, const float* __restrict__ ew, int* __restrict__ ecur,
    int2* __restrict__ csr,
    const int* __restrict__ pcnt, int* __restrict__ pcur, int* __restrict__ srun,
    int* __restrict__ ptot) {
    int b = blockIdx.x;
    if (b < 1250) { dev_scatter(b, ei, ew, ecur, csr); return; }
    dev_palloc2(b - 1250, pcnt, pcur, srun, ptot);
}

// K4: [gemm L1 628 | pscat3 2048] = 2676 blocks -- fine scatter hides under the layer-1 GEMM
__global__ __launch_bounds__(256) void k_fuse4(
    const ushort_t* __restrict__ ash, const ushort_t* __restrict__ asl,
    const ushort_t* __restrict__ r1h, const ushort_t* __restrict__ o1h,
    ushort_t* __restrict__ Pb, float* __restrict__ Rb,
    const int2* __restrict__ stage, const int* __restrict__ gcur,
    int* __restrict__ pcur, int2* __restrict__ parr) {
    int b = blockIdx.x;
    if (b < 628) {
        dev_gemm<false, ushort_t, float>(b % GXM, b / GXM, ash, asl, r1h, o1h, nullptr,
                                         Pb, Rb, N_NODES, 256, 256);
        return;
    }
    dev_pscat3(b - 628, stage, gcur, pcur, parr);
}

// standalone GEMM wrapper (layers 2, 3, decoder tables)
template <bool ALO, typename T1, typename T2>
__global__ __launch_bounds__(256) void k_gemm_bf(const ushort_t* __restrict__ Ahi, const ushort_t* __restrict__ Alo,
                                                 const ushort_t* __restrict__ W1hi, const ushort_t* __restrict__ W2hi,
                                                 const float* __restrict__ bias1,
                                                 T1* __restrict__ out1, T2* __restrict__ out2,
                                                 int M, int K, int NC) {
    dev_gemm<ALO, T1, T2>(blockIdx.x, blockIdx.y, Ahi, Alo, W1hi, W2hi, bias1, out1, out2, M, K, NC);
}

// ---------------- fused agg epilogue: 4-edge unroll + csr index software-prefetch
// (FP add order identical to the 2-wide loop: acc += (w0*p0 + w1*p1); acc += (w2*p2 + w3*p3)) ----------------
template <int C, bool RELU, bool EMITLO>
__global__ __launch_bounds__(256) void k_aggf(const ushort_t* __restrict__ P, const float* __restrict__ R,
                                              const float* __restrict__ bias,
                                              const int* __restrict__ ebase, const int* __restrict__ eend,
                                              const int2* __restrict__ csr,
                                              ushort_t* __restrict__ hh, ushort_t* __restrict__ hl) {
    int wave = (blockIdx.x * 256 + threadIdx.x) >> 6;
    int lane = threadIdx.x & 63;
    if (wave >= N_NODES) return;
    int beg = ebase[wave], end = eend[wave];
    if constexpr (C == 256) {
        int col = lane * 4;
        float4 acc = {0.f, 0.f, 0.f, 0.f};
        int e = beg;
        int2 p0, p1, p2, p3;
        if (e + 3 < end) { p0 = csr[e]; p1 = csr[e + 1]; p2 = csr[e + 2]; p3 = csr[e + 3]; }
        for (; e + 3 < end; ) {
            float w0 = __int_as_float(p0.y), w1 = __int_as_float(p1.y);
            float w2 = __int_as_float(p2.y), w3 = __int_as_float(p3.y);
            uint2 u0 = *(const uint2*)&P[(size_t)p0.x * 256 + col];
            uint2 u1 = *(const uint2*)&P[(size_t)p1.x * 256 + col];
            uint2 u2 = *(const uint2*)&P[(size_t)p2.x * 256 + col];
            uint2 u3 = *(const uint2*)&P[(size_t)p3.x * 256 + col];
            int en = e + 4;
            if (en + 3 < end) { p0 = csr[en]; p1 = csr[en + 1]; p2 = csr[en + 2]; p3 = csr[en + 3]; }
            acc.x += w0 * blo(u0.x) + w1 * blo(u1.x);
            acc.y += w0 * bhi(u0.x) + w1 * bhi(u1.x);
            acc.z += w0 * blo(u0.y) + w1 * blo(u1.y);
            acc.w += w0 * bhi(u0.y) + w1 * bhi(u1.y);
            acc.x += w2 * blo(u2.x) + w3 * blo(u3.x);
            acc.y += w2 * bhi(u2.x) + w3 * bhi(u3.x);
            acc.z += w2 * blo(u2.y) + w3 * blo(u3.y);
            acc.w += w2 * bhi(u2.y) + w3 * bhi(u3.y);
            e = en;
        }
        for (; e + 1 < end; e += 2) {
            int2 q0 = csr[e], q1 = csr[e + 1];
            float w0 = __int_as_float(q0.y), w1 = __int_as_float(q1.y);
            uint2 u0 = *(const uint2*)&P[(size_t)q0.x * 256 + col];
            uint2 u1 = *(const uint2*)&P[(size_t)q1.x * 256 + col];
            acc.x += w0 * blo(u0.x) + w1 * blo(u1.x);
            acc.y += w0 * bhi(u0.x) + w1 * bhi(u1.x);
            acc.z += w0 * blo(u0.y) + w1 * blo(u1.y);
            acc.w += w0 * bhi(u0.y) + w1 * bhi(u1.y);
        }
        if (e < end) {
            int2 q0 = csr[e];
            float w0 = __int_as_float(q0.y);
            uint2 u0 = *(const uint2*)&P[(size_t)q0.x * 256 + col];
            acc.x += w0 * blo(u0.x); acc.y += w0 * bhi(u0.x);
            acc.z += w0 * blo(u0.y); acc.w += w0 * bhi(u0.y);
        }
        float4 rr = *(const float4*)&R[(size_t)wave * 256 + col];
        float4 bb = *(const float4*)&bias[col];
        float o[4];
        o[0] = acc.x + rr.x + bb.x; o[1] = acc.y + rr.y + bb.y;
        o[2] = acc.z + rr.z + bb.z; o[3] = acc.w + rr.w + bb.w;
        if (RELU) {
#pragma unroll
            for (int j = 0; j < 4; j++) o[j] = fmaxf(o[j], 0.f);
        }
        union { uint2 v; ushort_t u[4]; } H, L;
#pragma unroll
        for (int j = 0; j < 4; j++) {
            ushort_t h = f2bf(o[j]);
            H.u[j] = h;
            if (EMITLO) L.u[j] = f2bf(o[j] - bf2f(h));
        }
        *(uint2*)&hh[(size_t)wave * 256 + col] = H.v;
        if (EMITLO) *(uint2*)&hl[(size_t)wave * 256 + col] = L.v;
    } else {
        int col = lane * 2;
        float2 acc = {0.f, 0.f};
        int e = beg;
        int2 p0, p1, p2, p3;
        if (e + 3 < end) { p0 = csr[e]; p1 = csr[e + 1]; p2 = csr[e + 2]; p3 = csr[e + 3]; }
        for (; e + 3 < end; ) {
            float w0 = __int_as_float(p0.y), w1 = __int_as_float(p1.y);
            float w2 = __int_as_float(p2.y), w3 = __int_as_float(p3.y);
            unsigned int u0 = *(const unsigned int*)&P[(size_t)p0.x * 128 + col];
            unsigned int u1 = *(const unsigned int*)&P[(size_t)p1.x * 128 + col];
            unsigned int u2 = *(const unsigned int*)&P[(size_t)p2.x * 128 + col];
            unsigned int u3 = *(const unsigned int*)&P[(size_t)p3.x * 128 + col];
            int en = e + 4;
            if (en + 3 < end) { p0 = csr[en]; p1 = csr[en + 1]; p2 = csr[en + 2]; p3 = csr[en + 3]; }
            acc.x += w0 * blo(u0) + w1 * blo(u1);
            acc.y += w0 * bhi(u0) + w1 * bhi(u1);
            acc.x += w2 * blo(u2) + w3 * blo(u3);
            acc.y += w2 * bhi(u2) + w3 * bhi(u3);
            e = en;
        }
        for (; e + 1 < end; e += 2) {
            int2 q0 = csr[e], q1 = csr[e + 1];
            float w0 = __int_as_float(q0.y), w1 = __int_as_float(q1.y);
            unsigned int u0 = *(const unsigned int*)&P[(size_t)q0.x * 128 + col];
            unsigned int u1 = *(const unsigned int*)&P[(size_t)q1.x * 128 + col];
            acc.x += w0 * blo(u0) + w1 * blo(u1);
            acc.y += w0 * bhi(u0) + w1 * bhi(u1);
        }
        if (e < end) {
            int2 q0 = csr[e];
            float w0 = __int_as_float(q0.y);
            unsigned int u0 = *(const unsigned int*)&P[(size_t)q0.x * 128 + col];
            acc.x += w0 * blo(u0); acc.y += w0 * bhi(u0);
        }
        float2 rr = *(const float2*)&R[(size_t)wave * 128 + col];
        float2 bb = *(const float2*)&bias[col];
        float o0 = acc.x + rr.x + bb.x, o1 = acc.y + rr.y + bb.y;
        if (RELU) { o0 = fmaxf(o0, 0.f); o1 = fmaxf(o1, 0.f); }
        union { unsigned int v; ushort_t u[2]; } H, L;
        ushort_t h0 = f2bf(o0), h1 = f2bf(o1);
        H.u[0] = h0; H.u[1] = h1;
        *(unsigned int*)&hh[(size_t)wave * 128 + col] = H.v;
        if (EMITLO) {
            L.u[0] = f2bf(o0 - bf2f(h0)); L.u[1] = f2bf(o1 - bf2f(h1));
            *(unsigned int*)&hl[(size_t)wave * 128 + col] = L.v;
        }
    }
}

// ---------------- decoder: 8 pairs/iter, index software-prefetch, single 9-shuffle merge ----------------
// Split into range-partitioned dispatches via jbase/Jtot (visibility + same numerics).
__device__ inline float dot8relu_f16(uint4 ua, uint4 ub, const half2_t* w2p) {
    half2_t z = {(_Float16)0.f, (_Float16)0.f};
    float r = 0.f;
    half2_t s;
    s = __builtin_elementwise_max(__builtin_bit_cast(half2_t, ua.x) + __builtin_bit_cast(half2_t, ub.x), z);
    r = __builtin_amdgcn_fdot2(s, w2p[0], r, false);
    s = __builtin_elementwise_max(__builtin_bit_cast(half2_t, ua.y) + __builtin_bit_cast(half2_t, ub.y), z);
    r = __builtin_amdgcn_fdot2(s, w2p[1], r, false);
    s = __builtin_elementwise_max(__builtin_bit_cast(half2_t, ua.z) + __builtin_bit_cast(half2_t, ub.z), z);
    r = __builtin_amdgcn_fdot2(s, w2p[2], r, false);
    s = __builtin_elementwise_max(__builtin_bit_cast(half2_t, ua.w) + __builtin_bit_cast(half2_t, ub.w), z);
    r = __builtin_amdgcn_fdot2(s, w2p[3], r, false);
    return r;
}

__global__ __launch_bounds__(256) void k_decoder(const _Float16* __restrict__ Ab, const _Float16* __restrict__ Bb,
                                                 const int2* __restrict__ parr, const int* __restrict__ srun,
                                                 const int* __restrict__ ptot,
                                                 const float* __restrict__ Wd2, const float* __restrict__ bd2,
                                                 float* __restrict__ out, int jbase, int Jtot) {
    int x = blockIdx.x & 7;          // d-bucket == XCD (B-slice 640 KB stays in this XCD's L2)
    int j = jbase + (blockIdx.x >> 3);   // slice within d-bucket (global slice index)
    int hw = threadIdx.x >> 5;       // half-wave id in block (0..7)
    int l32 = threadIdx.x & 31;
    int col = l32 * 8;               // 8 f16 = 16 B per lane
    half2_t w2p[4];
#pragma unroll
    for (int q = 0; q < 4; q++) {
        half2_t t = {(_Float16)Wd2[col + 2 * q], (_Float16)Wd2[col + 2 * q + 1]};
        w2p[q] = t;
    }
    float b2 = bd2[0];
    int G = Jtot * 8;                // half-waves per d-bucket (across all partitions)
    int g = j * 8 + hw;
    int ngrp = ptot[x * 16] >> 2;    // padded 4-pair groups in this bucket
    int ns = (ngrp + 1) >> 1;        // 8-pair supergroups; phantom tail reads 0xFF sentinels
    int s0 = (int)((long)ns * g / G);
    int s1 = (int)((long)ns * (g + 1) / G);
    const char* Bc = (const char*)Bb + (size_t)col * 2;   // lane's column base (byte)
    const char* Ac = (const char*)Ab + (size_t)col * 2;
    const int* sr = srun + x * (BSEG / 4);
    const int2* pb = parr + (size_t)x * BSEG;

    int cura = -1;
    uint4 acache;
    int sg = s0;
    int2 sr2; int4 q0, q1, q2, q3;
    if (sg < s1) {                    // prologue: load first iteration's indices
        sr2 = *(const int2*)&sr[sg * 2];
        int i0 = sg * 8;
        q0 = *(const int4*)&pb[i0];
        q1 = *(const int4*)&pb[i0 + 2];
        q2 = *(const int4*)&pb[i0 + 4];
        q3 = *(const int4*)&pb[i0 + 6];
    }
    for (; sg < s1; ) {
        int aoff0 = max(sr2.x, 0);                // sentinel -1 -> row 0 (pm blocks store)
        int aoff1 = max(sr2.y, 0);
        if (aoff0 != cura) { acache = *(const uint4*)(Ac + aoff0); cura = aoff0; }
        uint4 a0 = acache;
        if (aoff1 != cura) { acache = *(const uint4*)(Ac + aoff1); cura = aoff1; }
        uint4 a1 = acache;
        int d0 = max(q0.x, 0), d1 = max(q0.z, 0);
        int d2 = max(q1.x, 0), d3 = max(q1.z, 0);
        int d4 = max(q2.x, 0), d5 = max(q2.z, 0);
        int d6 = max(q3.x, 0), d7 = max(q3.z, 0);
        uint4 b0 = *(const uint4*)(Bc + d0);      // 8 independent gathers in flight
        uint4 b1 = *(const uint4*)(Bc + d1);
        uint4 b2v = *(const uint4*)(Bc + d2);
        uint4 b3 = *(const uint4*)(Bc + d3);
        uint4 b4 = *(const uint4*)(Bc + d4);
        uint4 b5 = *(const uint4*)(Bc + d5);
        uint4 b6 = *(const uint4*)(Bc + d6);
        uint4 b7 = *(const uint4*)(Bc + d7);
        // keep current pm's before overwriting index regs
        int m0 = q0.y, m1 = q0.w, m2 = q1.y, m3 = q1.w;
        int m4 = q2.y, m5 = q2.w, m6 = q3.y, m7 = q3.w;
        // software pipeline: issue NEXT iteration's index loads before the dots consume gathers
        int sgn = sg + 1;
        if (sgn < s1) {
            sr2 = *(const int2*)&sr[sgn * 2];
            int i0n = sgn * 8;
            q0 = *(const int4*)&pb[i0n];
            q1 = *(const int4*)&pb[i0n + 2];
            q2 = *(const int4*)&pb[i0n + 4];
            q3 = *(const int4*)&pb[i0n + 6];
        }
        float r0 = dot8relu_f16(a0, b0, w2p);
        float r1 = dot8relu_f16(a0, b1, w2p);
        float r2 = dot8relu_f16(a0, b2v, w2p);
        float r3 = dot8relu_f16(a0, b3, w2p);
        float r4 = dot8relu_f16(a1, b4, w2p);
        float r5 = dot8relu_f16(a1, b5, w2p);
        float r6 = dot8relu_f16(a1, b6, w2p);
        float r7 = dot8relu_f16(a1, b7, w2p);
        // merged 8-value butterfly: 9 shuffles for 8 pairs
        float u01 = (l32 & 1) ? r1 : r0, v01 = (l32 & 1) ? r0 : r1;
        u01 += __shfl_xor(v01, 1, 32);
        float u23 = (l32 & 1) ? r3 : r2, v23 = (l32 & 1) ? r2 : r3;
        u23 += __shfl_xor(v23, 1, 32);
        float u45 = (l32 & 1) ? r5 : r4, v45 = (l32 & 1) ? r4 : r5;
        u45 += __shfl_xor(v45, 1, 32);
        float u67 = (l32 & 1) ? r7 : r6, v67 = (l32 & 1) ? r6 : r7;
        u67 += __shfl_xor(v67, 1, 32);
        float w03 = (l32 & 2) ? u23 : u01, wv03 = (l32 & 2) ? u01 : u23;
        w03 += __shfl_xor(wv03, 2, 32);
        float w47 = (l32 & 2) ? u67 : u45, wv47 = (l32 & 2) ? u45 : u67;
        w47 += __shfl_xor(wv47, 2, 32);
        float v = (l32 & 4) ? w47 : w03, vv = (l32 & 4) ? w03 : w47;
        v += __shfl_xor(vv, 4, 32);
        v += __shfl_xor(v, 8, 32);
        v += __shfl_xor(v, 16, 32);
        // lane k (0..7) holds pair k's sum; select its pm
        int pA = (l32 & 1) ? m1 : m0;
        int pB = (l32 & 1) ? m3 : m2;
        int pC = (l32 & 1) ? m5 : m4;
        int pD = (l32 & 1) ? m7 : m6;
        int pAB = (l32 & 2) ? pB : pA;
        int pCD = (l32 & 2) ? pD : pC;
        int p = (l32 & 4) ? pCD : pAB;
        if (l32 < 8 && p >= 0) out[p] = v + b2;
        sg = sgn;
    }
}

extern "C" void kernel_launch(void* const* d_in, const int* in_sizes, int n_in,
                              void* d_out, int out_size, void* d_ws, size_t ws_size,
                              hipStream_t stream) {
    const float* x   = (const float*)d_in[0];
    const int*   ei  = (const int*)d_in[1];
    const float* ew  = (const float*)d_in[2];
    const int*   el  = (const int*)d_in[3];
    const float* Wr1 = (const float*)d_in[4];
    const float* br1 = (const float*)d_in[5];
    const float* Wo1 = (const float*)d_in[6];
    const float* Wr2 = (const float*)d_in[7];
    const float* br2 = (const float*)d_in[8];
    const float* Wo2 = (const float*)d_in[9];
    const float* Wr3 = (const float*)d_in[10];
    const float* br3 = (const float*)d_in[11];
    const float* Wo3 = (const float*)d_in[12];
    const float* Wd1 = (const float*)d_in[13];
    const float* bd1 = (const float*)d_in[14];
    const float* Wd2 = (const float*)d_in[15];
    const float* bd2 = (const float*)d_in[16];
    float* out = (float*)d_out;

    char* ws = (char*)d_ws;
    size_t o = 0;
    auto alloc = [&](size_t bytes) { size_t p = o; o += (bytes + 255) & ~(size_t)255; return (void*)(ws + p); };
    // cnt + pcnt + etot + ptot + gcur adjacent -> single zero-memset
    int*     cnt     = (int*)alloc(N_NODES * 4);
    int*     pcnt    = (int*)alloc(NRUNS2 * 4);
    int*     etot    = (int*)alloc(4);
    int*     ptot    = (int*)alloc(8 * 16 * 4);
    int*     gcur    = (int*)alloc(64 * 16 * 4);
    size_t   zero_bytes = (size_t)((char*)gcur - (char*)cnt) + 64 * 16 * 4;
    // parr + srun adjacent -> single 0xFF fill (folded into k_fuse1)
    int2*    parr    = (int2*)alloc((size_t)NBUCK * BSEG * 8);
    int*     srun    = (int*)alloc((size_t)NBUCK * (BSEG / 4) * 4);
    int2*    stage   = (int2*)alloc((size_t)64 * BCAP * 8);
    int2*    csr     = (int2*)alloc((size_t)N_EDGES * 8);
    int*     ebase   = (int*)alloc(N_NODES * 4);
    int*     eend    = (int*)alloc(N_NODES * 4);
    int*     ecur    = (int*)alloc(N_NODES * 4);
    int*     pcur    = (int*)alloc(NRUNS2 * 4);
    // activation buffers (hi always; lo only used for z)
    ushort_t* ash = (ushort_t*)alloc((size_t)N_NODES * 256 * 2);
    ushort_t* asl = (ushort_t*)alloc((size_t)N_NODES * 256 * 2);
    // GEMM outputs: P bf16 (later Atab f16), R fp32 (later Btab f16)
    ushort_t* Pb  = (ushort_t*)alloc((size_t)N_NODES * 256 * 2);
    float*    Rb  = (float*)alloc((size_t)N_NODES * 256 * 4);
    // pre-split transposed weights (hi only)
    ushort_t* r1h = (ushort_t*)alloc(256 * 256 * 2);
    ushort_t* o1h = (ushort_t*)alloc(256 * 256 * 2);
    ushort_t* r2h = (ushort_t*)alloc(128 * 256 * 2);
    ushort_t* o2h = (ushort_t*)alloc(128 * 256 * 2);
    ushort_t* r3h = (ushort_t*)alloc(128 * 128 * 2);
    ushort_t* o3h = (ushort_t*)alloc(128 * 128 * 2);
    ushort_t* dah = (ushort_t*)alloc(256 * 128 * 2);
    ushort_t* dbh = (ushort_t*)alloc(256 * 128 * 2);
    _Float16* Atab = (_Float16*)Pb;
    _Float16* Btab = (_Float16*)Rb;

    hipMemsetAsync(cnt, 0, zero_bytes, stream);

    // K1: pstage | edge-hist | xsplit | wsplit | parr/srun 0xFF fill (all independent)
    k_fuse1<<<8099, 256, 0, stream>>>(el, gcur, stage, ei, cnt, x, ash, (uint4*)parr,
                                      Wr1, Wo1, Wr2, Wo2, Wr3, Wo3, Wd1,
                                      r1h, o1h, r2h, o2h, r3h, o3h, dah, dbh);
    // K2: edge bump-alloc | bucket-local fine histogram
    k_fuse2<<<2088, 256, 0, stream>>>(cnt, ebase, eend, ecur, etot, stage, gcur, pcnt);
    // K3: edge scatter | per-bucket run alloc (+srun)
    k_fuse3<<<1570, 256, 0, stream>>>(ei, ew, ecur, csr, pcnt, pcur, srun, ptot);
    // K4: layer-1 dual GEMM || bucket-local fine scatter
    k_fuse4<<<2676, 256, 0, stream>>>(ash, asl, r1h, o1h, Pb, Rb, stage, gcur, pcur, parr);

    k_aggf<256, true, false><<<2500, 256, 0, stream>>>(Pb, Rb, br1, ebase, eend, csr, ash, asl);

    k_gemm_bf<false, ushort_t, float><<<dim3(GXM, 2), 256, 0, stream>>>(ash, asl, r2h, o2h, nullptr,
                                                                        Pb, Rb, N_NODES, 256, 128);
    k_aggf<128, true, false><<<2500, 256, 0, stream>>>(Pb, Rb, br2, ebase, eend, csr, ash, asl);

    k_gemm_bf<false, ushort_t, float><<<dim3(GXM, 2), 256, 0, stream>>>(ash, asl, r3h, o3h, nullptr,
                                                                        Pb, Rb, N_NODES, 128, 128);
    k_aggf<128, false, true><<<2500, 256, 0, stream>>>(Pb, Rb, br3, ebase, eend, csr, ash, asl);

    // Decoder tables (f16): Atab = z@Wd1_top + bd1, Btab = z@Wd1_bot  (A = z hi/lo)
    k_gemm_bf<true, _Float16, _Float16><<<dim3(GXM, 4), 256, 0, stream>>>(ash, asl, dah, dbh, bd1,
                                                                          Atab, Btab, N_NODES, 128, 256);

    // Decoder: two half-range dispatches (4096 blocks each, backfill TLP restored; reveals mid kernels)
    k_decoder<<<4096, 256, 0, stream>>>(Atab, Btab, parr, srun, ptot, Wd2, bd2, out, 0, 1024);
    k_decoder<<<4096, 256, 0, stream>>>(Atab, Btab, parr, srun, ptot, Wd2, bd2, out, 512, 1024);
}

// Round 9
// 351.867 us; speedup vs baseline: 1.0348x; 1.0348x over previous
//
#include <hip/hip_runtime.h>

#define N_NODES 10000
#define N_EDGES 320000
#define N_PAIRS 1000000
#define NBUCK 8
#define DBW 1250            // d-bucket width (N_NODES / 8)
#define SBW 1250            // s-bucket width for coarse stage
#define SMAX 10240          // run-index stride per bucket (40 x 256: alloc chunks never straddle buckets)
#define NRUNS2 (NBUCK * SMAX)     // 81920
#define BSEG 160000         // per-bucket parr segment (expected ~142.5K padded, 5-sigma safe)
#define PSB 512             // pstage producer blocks
#define SLOTB 76            // per (bucket, producer) fixed slot capacity (Poisson(32), P(ovfl)~1e-5)
#define GXM 157             // (N_NODES + 63) / 64
#define FILL16 720000       // (NBUCK*BSEG*8 + NBUCK*(BSEG/4)*4) / 16 -- parr+srun 0xFF fill, uint4 units

typedef unsigned short ushort_t;
typedef __attribute__((ext_vector_type(8))) short short8;
typedef __attribute__((ext_vector_type(4))) float floatx4;
typedef _Float16 half2_t __attribute__((ext_vector_type(2)));

__device__ inline float blo(unsigned int u) { return __uint_as_float(u << 16); }
__device__ inline float bhi(unsigned int u) { return __uint_as_float(u & 0xffff0000u); }
__device__ inline ushort_t f2bf(float f) {
    unsigned int u = __float_as_uint(f);
    unsigned int r = (u + 0x7fffu + ((u >> 16) & 1u)) >> 16;
    return (ushort_t)r;
}
__device__ inline float bf2f(ushort_t b) { return __uint_as_float(((unsigned int)b) << 16); }
__device__ inline void stout(float* p, float v) { *p = v; }
__device__ inline void stout(ushort_t* p, float v) { *p = f2bf(v); }
__device__ inline void stout(_Float16* p, float v) { *p = (_Float16)v; }

// ================= device bodies =================

// coarse 64-bucket scatter into PRIVATE fixed-capacity (bucket, block) segments.
// No global reservation atomics, no counting pass -- one LDS bump per pair.
__device__ void dev_pstage(int bid, const int* __restrict__ el,
                           int2* __restrict__ stage, int* __restrict__ scnt) {
    __shared__ int lcur[64];
    int t = threadIdx.x;
    if (t < 64) lcur[t] = 0;
    __syncthreads();
    const int STR = PSB * 256;       // 131072; 8 iterations cover 1M
    int i0 = bid * 256 + t;
#pragma unroll
    for (int k = 0; k < 8; k++) {
        int i = i0 + k * STR;
        if (i < N_PAIRS) {
            int s = el[i], d = el[N_PAIRS + i];
            int c = (d / DBW) * 8 + s / SBW;
            int r = atomicAdd(&lcur[c], 1);
            stage[((size_t)c * PSB + bid) * SLOTB + r] = make_int2(s | (d << 14), i);
        }
    }
    __syncthreads();
    if (t < 64) scnt[t * PSB + bid] = lcur[t];
}

__device__ void dev_hist(int bid, const int* __restrict__ ei, int* __restrict__ cnt) {
    int e = bid * 256 + threadIdx.x;
    if (e < N_EDGES) atomicAdd(&cnt[ei[N_EDGES + e]], 1);
}

__device__ void dev_xsplit(int bid, const float* __restrict__ x, ushort_t* __restrict__ xh) {
    int i = bid * 256 + threadIdx.x;
    if (i >= N_NODES * 256 / 4) return;
    float4 f = ((const float4*)x)[i];
    union { uint2 v; ushort_t u[4]; } H;
    H.u[0] = f2bf(f.x); H.u[1] = f2bf(f.y); H.u[2] = f2bf(f.z); H.u[3] = f2bf(f.w);
    ((uint2*)xh)[i] = H.v;
}

__device__ void dev_fill(int bid, uint4* __restrict__ dst) {
    int i = bid * 256 + threadIdx.x;
    if (i < FILL16) dst[i] = make_uint4(~0u, ~0u, ~0u, ~0u);
}

__device__ void dev_wsplit(int bx, int by, int bz,
                           const float* Wr1, const float* Wo1, const float* Wr2, const float* Wo2,
                           const float* Wr3, const float* Wo3, const float* Wd1,
                           ushort_t* r1h, ushort_t* o1h, ushort_t* r2h, ushort_t* o2h,
                           ushort_t* r3h, ushort_t* o3h, ushort_t* dah, ushort_t* dbh) {
    const float* src; ushort_t* dh; int K, NC;
    switch (bz) {
        case 0: src = Wr1; dh = r1h; K = 256; NC = 256; break;
        case 1: src = Wo1; dh = o1h; K = 256; NC = 256; break;
        case 2: src = Wr2; dh = r2h; K = 256; NC = 128; break;
        case 3: src = Wo2; dh = o2h; K = 256; NC = 128; break;
        case 4: src = Wr3; dh = r3h; K = 128; NC = 128; break;
        case 5: src = Wo3; dh = o3h; K = 128; NC = 128; break;
        case 6: src = Wd1;             dh = dah; K = 128; NC = 256; break;
        default: src = Wd1 + 128 * 256; dh = dbh; K = 128; NC = 256; break;
    }
    int tk = bx * 32, tn = by * 32;
    if (tk >= K || tn >= NC) return;
    __shared__ float tile[32][33];
    int tx = threadIdx.x & 31, ty0 = threadIdx.x >> 5;
#pragma unroll
    for (int r = 0; r < 4; r++) {
        int k = tk + ty0 + r * 8;
        tile[ty0 + r * 8][tx] = src[(size_t)k * NC + tn + tx];
    }
    __syncthreads();
#pragma unroll
    for (int r = 0; r < 4; r++) {
        int n = tn + ty0 + r * 8;
        dh[(size_t)n * K + tk + tx] = f2bf(tile[tx][ty0 + r * 8]);
    }
}

// block-local scan + one global atomicAdd per block (edges CSR alloc)
__device__ void dev_ealloc(int bid, const int* __restrict__ cnt,
                           int* __restrict__ base_, int* __restrict__ end_,
                           int* __restrict__ cur_, int* __restrict__ tot) {
    __shared__ int part[256];
    __shared__ int bbase;
    int t = threadIdx.x;
    int r = bid * 256 + t;
    int len = (r < N_NODES) ? cnt[r] : 0;
    part[t] = len;
    __syncthreads();
    for (int d = 1; d < 256; d <<= 1) {
        int v = (t >= d) ? part[t - d] : 0;
        __syncthreads();
        part[t] += v;
        __syncthreads();
    }
    if (t == 255) bbase = atomicAdd(tot, part[255]);
    __syncthreads();
    int excl = (t == 0) ? 0 : part[t - 1];
    if (r < N_NODES) {
        int b = bbase + excl;
        base_[r] = b;
        cur_[r] = b;
        end_[r] = b + len;
    }
}

// bucket-local fine histogram over private segments; wave-per-segment.
__device__ void dev_phist2(int vb, const int2* __restrict__ stage, const int* __restrict__ scnt,
                           int* __restrict__ pcnt) {
    int c = vb & 63;
    int j = vb >> 6;                 // 0..31
    int x = c >> 3;
    int w = threadIdx.x >> 6, l = threadIdx.x & 63;
#pragma unroll
    for (int k = 0; k < 4; k++) {
        int pb = j * 16 + w * 4 + k;
        int n = scnt[c * PSB + pb];
        const int2* sb = stage + ((size_t)c * PSB + pb) * SLOTB;
        for (int i = l; i < n; i += 64) {
            int s = sb[i].x & 16383;
            atomicAdd(&pcnt[x * SMAX + s], 1);
        }
    }
}

__device__ void dev_scatter(int bid, const int* __restrict__ ei, const float* __restrict__ ew,
                            int* __restrict__ ecur, int2* __restrict__ csr) {
    int e = bid * 256 + threadIdx.x;
    if (e < N_EDGES) {
        int d = ei[N_EDGES + e];
        int pos = atomicAdd(&ecur[d], 1);
        csr[pos] = make_int2(ei[e], __float_as_int(ew[e]));
    }
}

// per-BUCKET bump alloc (runs x4-padded) + srun group table
__device__ void dev_palloc2(int bid, const int* __restrict__ pcnt,
                            int* __restrict__ pcur, int* __restrict__ srun,
                            int* __restrict__ ptot) {
    __shared__ int part[256];
    __shared__ int bbase;
    int t = threadIdx.x;
    int r = bid * 256 + t;
    int x = bid / (SMAX / 256);
    int s = r - x * SMAX;
    int len = pcnt[r];
    int pad = (len + 3) & ~3;
    part[t] = pad;
    __syncthreads();
    for (int d = 1; d < 256; d <<= 1) {
        int v = (t >= d) ? part[t - d] : 0;
        __syncthreads();
        part[t] += v;
        __syncthreads();
    }
    if (t == 255) bbase = atomicAdd(&ptot[x * 16], part[255]);
    __syncthreads();
    int excl = (t == 0) ? 0 : part[t - 1];
    int b = bbase + excl;
    pcur[r] = x * BSEG + b;
    int aoff = s << 9;
    int* sg = srun + x * (BSEG / 4);
#pragma clang loop unroll(disable)
    for (int gq = b >> 2, ge = (b + pad) >> 2; gq < ge; ++gq) sg[gq] = aoff;
}

// bucket-local fine scatter over private segments; wave-per-segment.
__device__ void dev_pscat3(int vb, const int2* __restrict__ stage, const int* __restrict__ scnt,
                           int* __restrict__ pcur, int2* __restrict__ parr) {
    int c = vb & 63;
    int j = vb >> 6;
    int x = c >> 3;
    int w = threadIdx.x >> 6, l = threadIdx.x & 63;
#pragma unroll
    for (int k = 0; k < 4; k++) {
        int pb = j * 16 + w * 4 + k;
        int n = scnt[c * PSB + pb];
        const int2* sb = stage + ((size_t)c * PSB + pb) * SLOTB;
        for (int i = l; i < n; i += 64) {
            int2 p = sb[i];
            int s = p.x & 16383, d = p.x >> 14;
            int pos = atomicAdd(&pcur[x * SMAX + s], 1);
            parr[pos] = make_int2(d << 9, p.y);
        }
    }
}

// ---------------- MFMA dual-GEMM body ----------------
template <bool ALO, typename T1, typename T2>
__device__ void dev_gemm(int bx, int by,
                         const ushort_t* __restrict__ Ahi, const ushort_t* __restrict__ Alo,
                         const ushort_t* __restrict__ W1hi, const ushort_t* __restrict__ W2hi,
                         const float* __restrict__ bias1,
                         T1* __restrict__ out1, T2* __restrict__ out2,
                         int M, int K, int NC) {
    __shared__ ushort_t sAh[64][32], sAl[ALO ? 64 : 1][32];
    __shared__ ushort_t s1h[64][32], s2h[64][32];

    int tid = threadIdx.x;
    int lane = tid & 63, wid = tid >> 6;
    int wm = wid >> 1, wn = wid & 1;
    int l15 = lane & 15, quad = lane >> 4;
    int row0 = bx * 64, col0 = by * 64;

    int srow = tid >> 2, schunk = (tid & 3) * 8;
    int arow = row0 + srow; if (arow > M - 1) arow = M - 1;
    const ushort_t* gAh = Ahi + (size_t)arow * K + schunk;
    const ushort_t* gAl = Alo + (size_t)arow * K + schunk;
    int wrow = col0 + srow;
    const ushort_t* g1h = W1hi + (size_t)wrow * K + schunk;
    const ushort_t* g2h = W2hi + (size_t)wrow * K + schunk;

    floatx4 acc1[2][2] = {}, acc2[2][2] = {};

    for (int kk = 0; kk < K; kk += 32) {
        *(short8*)&sAh[srow][schunk] = *(const short8*)(gAh + kk);
        if (ALO) *(short8*)&sAl[srow][schunk] = *(const short8*)(gAl + kk);
        *(short8*)&s1h[srow][schunk] = *(const short8*)(g1h + kk);
        *(short8*)&s2h[srow][schunk] = *(const short8*)(g2h + kk);
        __syncthreads();

        short8 ah[2], al[2], b1h[2], b2h[2];
#pragma unroll
        for (int t = 0; t < 2; t++) {
            int ar = wm * 32 + t * 16 + l15;
            ah[t] = *(const short8*)&sAh[ar][quad * 8];
            if (ALO) al[t] = *(const short8*)&sAl[ar][quad * 8];
            int bc = wn * 32 + t * 16 + l15;
            b1h[t] = *(const short8*)&s1h[bc][quad * 8];
            b2h[t] = *(const short8*)&s2h[bc][quad * 8];
        }
#pragma unroll
        for (int tm = 0; tm < 2; tm++)
#pragma unroll
            for (int tn = 0; tn < 2; tn++) {
                acc1[tm][tn] = __builtin_amdgcn_mfma_f32_16x16x32_bf16(ah[tm], b1h[tn], acc1[tm][tn], 0, 0, 0);
                acc2[tm][tn] = __builtin_amdgcn_mfma_f32_16x16x32_bf16(ah[tm], b2h[tn], acc2[tm][tn], 0, 0, 0);
                if (ALO) {
                    acc1[tm][tn] = __builtin_amdgcn_mfma_f32_16x16x32_bf16(al[tm], b1h[tn], acc1[tm][tn], 0, 0, 0);
                    acc2[tm][tn] = __builtin_amdgcn_mfma_f32_16x16x32_bf16(al[tm], b2h[tn], acc2[tm][tn], 0, 0, 0);
                }
            }
        __syncthreads();
    }

    // C/D layout: col = lane&15, row = quad*4 + reg
#pragma unroll
    for (int tm = 0; tm < 2; tm++) {
#pragma unroll
        for (int tn = 0; tn < 2; tn++) {
            int gc = col0 + wn * 32 + tn * 16 + l15;
            float bv = bias1 ? bias1[gc] : 0.f;
#pragma unroll
            for (int reg = 0; reg < 4; reg++) {
                int gr = row0 + wm * 32 + tm * 16 + quad * 4 + reg;
                if (gr >= M) continue;
                stout(&out1[(size_t)gr * NC + gc], acc1[tm][tn][reg] + bv);
                stout(&out2[(size_t)gr * NC + gc], acc2[tm][tn][reg]);
            }
        }
    }
}

// ================= fused dispatches =================

// K1: [pstage 512 | hist 1250 | xsplit 2500 | wsplit 512 | parr/srun 0xFF fill 2813] = 7587 blocks
__global__ __launch_bounds__(256) void k_fuse1(
    const int* __restrict__ el, int2* __restrict__ stage, int* __restrict__ scnt,
    const int* __restrict__ ei, int* __restrict__ cnt,
    const float* __restrict__ x, ushort_t* __restrict__ ash,
    uint4* __restrict__ fillbase,
    const float* Wr1, const float* Wo1, const float* Wr2, const float* Wo2,
    const float* Wr3, const float* Wo3, const float* Wd1,
    ushort_t* r1h, ushort_t* o1h, ushort_t* r2h, ushort_t* o2h,
    ushort_t* r3h, ushort_t* o3h, ushort_t* dah, ushort_t* dbh) {
    int b = blockIdx.x;
    if (b < PSB) { dev_pstage(b, el, stage, scnt); return; }
    b -= PSB;
    if (b < 1250) { dev_hist(b, ei, cnt); return; }
    b -= 1250;
    if (b < 2500) { dev_xsplit(b, x, ash); return; }
    b -= 2500;
    if (b < 512) {
        dev_wsplit(b & 7, (b >> 3) & 7, b >> 6, Wr1, Wo1, Wr2, Wo2, Wr3, Wo3, Wd1,
                   r1h, o1h, r2h, o2h, r3h, o3h, dah, dbh);
        return;
    }
    dev_fill(b - 512, fillbase);
}

// K2: [edge alloc 40 | phist2 2048] = 2088 blocks
__global__ __launch_bounds__(256) void k_fuse2(
    const int* __restrict__ cnt, int* __restrict__ ebase, int* __restrict__ eend,
    int* __restrict__ ecur, int* __restrict__ etot,
    const int2* __restrict__ stage, const int* __restrict__ scnt, int* __restrict__ pcnt) {
    int b = blockIdx.x;
    if (b < 40) { dev_ealloc(b, cnt, ebase, eend, ecur, etot); return; }
    dev_phist2(b - 40, stage, scnt, pcnt);
}

// K3: [edge scatter 1250 | palloc2 320] = 1570 blocks
__global__ __launch_bounds__(256) void k_fuse3(
    const int* __restrict__ ei, const float* __restrict__ ew, int* __restrict__ ecur,
    int2* __restrict__ csr,
    const int* __restrict__ pcnt, int* __restrict__ pcur, int* __restrict__ srun,
    int* __restrict__ ptot) {
    int b = blockIdx.x;
    if (b < 1250) { dev_scatter(b, ei, ew, ecur, csr); return; }
    dev_palloc2(b - 1250, pcnt, pcur, srun, ptot);
}

// K4: [gemm L1 628 | pscat3 2048] = 2676 blocks -- fine scatter hides under the layer-1 GEMM
__global__ __launch_bounds__(256) void k_fuse4(
    const ushort_t* __restrict__ ash, const ushort_t* __restrict__ asl,
    const ushort_t* __restrict__ r1h, const ushort_t* __restrict__ o1h,
    ushort_t* __restrict__ Pb, float* __restrict__ Rb,
    const int2* __restrict__ stage, const int* __restrict__ scnt,
    int* __restrict__ pcur, int2* __restrict__ parr) {
    int b = blockIdx.x;
    if (b < 628) {
        dev_gemm<false, ushort_t, float>(b % GXM, b / GXM, ash, asl, r1h, o1h, nullptr,
                                         Pb, Rb, N_NODES, 256, 256);
        return;
    }
    dev_pscat3(b - 628, stage, scnt, pcur, parr);
}

// standalone GEMM wrapper (layers 2, 3, decoder tables)
template <bool ALO, typename T1, typename T2>
__global__ __launch_bounds__(256) void k_gemm_bf(const ushort_t* __restrict__ Ahi, const ushort_t* __restrict__ Alo,
                                                 const ushort_t* __restrict__ W1hi, const ushort_t* __restrict__ W2hi,
                                                 const float* __restrict__ bias1,
                                                 T1* __restrict__ out1, T2* __restrict__ out2,
                                                 int M, int K, int NC) {
    dev_gemm<ALO, T1, T2>(blockIdx.x, blockIdx.y, Ahi, Alo, W1hi, W2hi, bias1, out1, out2, M, K, NC);
}

// ---------------- fused agg epilogue: 4-edge unroll + csr index software-prefetch
// (FP add order identical to the 2-wide loop: acc += (w0*p0 + w1*p1); acc += (w2*p2 + w3*p3)) ----------------
template <int C, bool RELU, bool EMITLO>
__global__ __launch_bounds__(256) void k_aggf(const ushort_t* __restrict__ P, const float* __restrict__ R,
                                              const float* __restrict__ bias,
                                              const int* __restrict__ ebase, const int* __restrict__ eend,
                                              const int2* __restrict__ csr,
                                              ushort_t* __restrict__ hh, ushort_t* __restrict__ hl) {
    int wave = (blockIdx.x * 256 + threadIdx.x) >> 6;
    int lane = threadIdx.x & 63;
    if (wave >= N_NODES) return;
    int beg = ebase[wave], end = eend[wave];
    if constexpr (C == 256) {
        int col = lane * 4;
        float4 acc = {0.f, 0.f, 0.f, 0.f};
        int e = beg;
        int2 p0, p1, p2, p3;
        if (e + 3 < end) { p0 = csr[e]; p1 = csr[e + 1]; p2 = csr[e + 2]; p3 = csr[e + 3]; }
        for (; e + 3 < end; ) {
            float w0 = __int_as_float(p0.y), w1 = __int_as_float(p1.y);
            float w2 = __int_as_float(p2.y), w3 = __int_as_float(p3.y);
            uint2 u0 = *(const uint2*)&P[(size_t)p0.x * 256 + col];
            uint2 u1 = *(const uint2*)&P[(size_t)p1.x * 256 + col];
            uint2 u2 = *(const uint2*)&P[(size_t)p2.x * 256 + col];
            uint2 u3 = *(const uint2*)&P[(size_t)p3.x * 256 + col];
            int en = e + 4;
            if (en + 3 < end) { p0 = csr[en]; p1 = csr[en + 1]; p2 = csr[en + 2]; p3 = csr[en + 3]; }
            acc.x += w0 * blo(u0.x) + w1 * blo(u1.x);
            acc.y += w0 * bhi(u0.x) + w1 * bhi(u1.x);
            acc.z += w0 * blo(u0.y) + w1 * blo(u1.y);
            acc.w += w0 * bhi(u0.y) + w1 * bhi(u1.y);
            acc.x += w2 * blo(u2.x) + w3 * blo(u3.x);
            acc.y += w2 * bhi(u2.x) + w3 * bhi(u3.x);
            acc.z += w2 * blo(u2.y) + w3 * blo(u3.y);
            acc.w += w2 * bhi(u2.y) + w3 * bhi(u3.y);
            e = en;
        }
        for (; e + 1 < end; e += 2) {
            int2 q0 = csr[e], q1 = csr[e + 1];
            float w0 = __int_as_float(q0.y), w1 = __int_as_float(q1.y);
            uint2 u0 = *(const uint2*)&P[(size_t)q0.x * 256 + col];
            uint2 u1 = *(const uint2*)&P[(size_t)q1.x * 256 + col];
            acc.x += w0 * blo(u0.x) + w1 * blo(u1.x);
            acc.y += w0 * bhi(u0.x) + w1 * bhi(u1.x);
            acc.z += w0 * blo(u0.y) + w1 * blo(u1.y);
            acc.w += w0 * bhi(u0.y) + w1 * bhi(u1.y);
        }
        if (e < end) {
            int2 q0 = csr[e];
            float w0 = __int_as_float(q0.y);
            uint2 u0 = *(const uint2*)&P[(size_t)q0.x * 256 + col];
            acc.x += w0 * blo(u0.x); acc.y += w0 * bhi(u0.x);
            acc.z += w0 * blo(u0.y); acc.w += w0 * bhi(u0.y);
        }
        float4 rr = *(const float4*)&R[(size_t)wave * 256 + col];
        float4 bb = *(const float4*)&bias[col];
        float o[4];
        o[0] = acc.x + rr.x + bb.x; o[1] = acc.y + rr.y + bb.y;
        o[2] = acc.z + rr.z + bb.z; o[3] = acc.w + rr.w + bb.w;
        if (RELU) {
#pragma unroll
            for (int j = 0; j < 4; j++) o[j] = fmaxf(o[j], 0.f);
        }
        union { uint2 v; ushort_t u[4]; } H, L;
#pragma unroll
        for (int j = 0; j < 4; j++) {
            ushort_t h = f2bf(o[j]);
            H.u[j] = h;
            if (EMITLO) L.u[j] = f2bf(o[j] - bf2f(h));
        }
        *(uint2*)&hh[(size_t)wave * 256 + col] = H.v;
        if (EMITLO) *(uint2*)&hl[(size_t)wave * 256 + col] = L.v;
    } else {
        int col = lane * 2;
        float2 acc = {0.f, 0.f};
        int e = beg;
        int2 p0, p1, p2, p3;
        if (e + 3 < end) { p0 = csr[e]; p1 = csr[e + 1]; p2 = csr[e + 2]; p3 = csr[e + 3]; }
        for (; e + 3 < end; ) {
            float w0 = __int_as_float(p0.y), w1 = __int_as_float(p1.y);
            float w2 = __int_as_float(p2.y), w3 = __int_as_float(p3.y);
            unsigned int u0 = *(const unsigned int*)&P[(size_t)p0.x * 128 + col];
            unsigned int u1 = *(const unsigned int*)&P[(size_t)p1.x * 128 + col];
            unsigned int u2 = *(const unsigned int*)&P[(size_t)p2.x * 128 + col];
            unsigned int u3 = *(const unsigned int*)&P[(size_t)p3.x * 128 + col];
            int en = e + 4;
            if (en + 3 < end) { p0 = csr[en]; p1 = csr[en + 1]; p2 = csr[en + 2]; p3 = csr[en + 3]; }
            acc.x += w0 * blo(u0) + w1 * blo(u1);
            acc.y += w0 * bhi(u0) + w1 * bhi(u1);
            acc.x += w2 * blo(u2) + w3 * blo(u3);
            acc.y += w2 * bhi(u2) + w3 * bhi(u3);
            e = en;
        }
        for (; e + 1 < end; e += 2) {
            int2 q0 = csr[e], q1 = csr[e + 1];
            float w0 = __int_as_float(q0.y), w1 = __int_as_float(q1.y);
            unsigned int u0 = *(const unsigned int*)&P[(size_t)q0.x * 128 + col];
            unsigned int u1 = *(const unsigned int*)&P[(size_t)q1.x * 128 + col];
            acc.x += w0 * blo(u0) + w1 * blo(u1);
            acc.y += w0 * bhi(u0) + w1 * bhi(u1);
        }
        if (e < end) {
            int2 q0 = csr[e];
            float w0 = __int_as_float(q0.y);
            unsigned int u0 = *(const unsigned int*)&P[(size_t)q0.x * 128 + col];
            acc.x += w0 * blo(u0); acc.y += w0 * bhi(u0);
        }
        float2 rr = *(const float2*)&R[(size_t)wave * 128 + col];
        float2 bb = *(const float2*)&bias[col];
        float o0 = acc.x + rr.x + bb.x, o1 = acc.y + rr.y + bb.y;
        if (RELU) { o0 = fmaxf(o0, 0.f); o1 = fmaxf(o1, 0.f); }
        union { unsigned int v; ushort_t u[2]; } H, L;
        ushort_t h0 = f2bf(o0), h1 = f2bf(o1);
        H.u[0] = h0; H.u[1] = h1;
        *(unsigned int*)&hh[(size_t)wave * 128 + col] = H.v;
        if (EMITLO) {
            L.u[0] = f2bf(o0 - bf2f(h0)); L.u[1] = f2bf(o1 - bf2f(h1));
            *(unsigned int*)&hl[(size_t)wave * 128 + col] = L.v;
        }
    }
}

// ---------------- decoder: 8 pairs/iter, index software-prefetch, single 9-shuffle merge ----------------
__device__ inline float dot8relu_f16(uint4 ua, uint4 ub, const half2_t* w2p) {
    half2_t z = {(_Float16)0.f, (_Float16)0.f};
    float r = 0.f;
    half2_t s;
    s = __builtin_elementwise_max(__builtin_bit_cast(half2_t, ua.x) + __builtin_bit_cast(half2_t, ub.x), z);
    r = __builtin_amdgcn_fdot2(s, w2p[0], r, false);
    s = __builtin_elementwise_max(__builtin_bit_cast(half2_t, ua.y) + __builtin_bit_cast(half2_t, ub.y), z);
    r = __builtin_amdgcn_fdot2(s, w2p[1], r, false);
    s = __builtin_elementwise_max(__builtin_bit_cast(half2_t, ua.z) + __builtin_bit_cast(half2_t, ub.z), z);
    r = __builtin_amdgcn_fdot2(s, w2p[2], r, false);
    s = __builtin_elementwise_max(__builtin_bit_cast(half2_t, ua.w) + __builtin_bit_cast(half2_t, ub.w), z);
    r = __builtin_amdgcn_fdot2(s, w2p[3], r, false);
    return r;
}

__global__ __launch_bounds__(256) void k_decoder(const _Float16* __restrict__ Ab, const _Float16* __restrict__ Bb,
                                                 const int2* __restrict__ parr, const int* __restrict__ srun,
                                                 const int* __restrict__ ptot,
                                                 const float* __restrict__ Wd2, const float* __restrict__ bd2,
                                                 float* __restrict__ out) {
    int x = blockIdx.x & 7;          // d-bucket == XCD (B-slice 640 KB stays in this XCD's L2)
    int j = blockIdx.x >> 3;         // slice within d-bucket
    int J = gridDim.x >> 3;
    int hw = threadIdx.x >> 5;       // half-wave id in block (0..7)
    int l32 = threadIdx.x & 31;
    int col = l32 * 8;               // 8 f16 = 16 B per lane
    half2_t w2p[4];
#pragma unroll
    for (int q = 0; q < 4; q++) {
        half2_t t = {(_Float16)Wd2[col + 2 * q], (_Float16)Wd2[col + 2 * q + 1]};
        w2p[q] = t;
    }
    float b2 = bd2[0];
    int G = J * 8;                   // half-waves per d-bucket
    int g = j * 8 + hw;
    int ngrp = ptot[x * 16] >> 2;    // padded 4-pair groups in this bucket
    int ns = (ngrp + 1) >> 1;        // 8-pair supergroups; phantom tail reads 0xFF sentinels
    int s0 = (int)((long)ns * g / G);
    int s1 = (int)((long)ns * (g + 1) / G);
    const char* Bc = (const char*)Bb + (size_t)col * 2;   // lane's column base (byte)
    const char* Ac = (const char*)Ab + (size_t)col * 2;
    const int* sr = srun + x * (BSEG / 4);
    const int2* pb = parr + (size_t)x * BSEG;

    int cura = -1;
    uint4 acache;
    int sg = s0;
    int2 sr2; int4 q0, q1, q2, q3;
    if (sg < s1) {                    // prologue: load first iteration's indices
        sr2 = *(const int2*)&sr[sg * 2];
        int i0 = sg * 8;
        q0 = *(const int4*)&pb[i0];
        q1 = *(const int4*)&pb[i0 + 2];
        q2 = *(const int4*)&pb[i0 + 4];
        q3 = *(const int4*)&pb[i0 + 6];
    }
    for (; sg < s1; ) {
        int aoff0 = max(sr2.x, 0);                // sentinel -1 -> row 0 (pm blocks store)
        int aoff1 = max(sr2.y, 0);
        if (aoff0 != cura) { acache = *(const uint4*)(Ac + aoff0); cura = aoff0; }
        uint4 a0 = acache;
        if (aoff1 != cura) { acache = *(const uint4*)(Ac + aoff1); cura = aoff1; }
        uint4 a1 = acache;
        int d0 = max(q0.x, 0), d1 = max(q0.z, 0);
        int d2 = max(q1.x, 0), d3 = max(q1.z, 0);
        int d4 = max(q2.x, 0), d5 = max(q2.z, 0);
        int d6 = max(q3.x, 0), d7 = max(q3.z, 0);
        uint4 b0 = *(const uint4*)(Bc + d0);      // 8 independent gathers in flight
        uint4 b1 = *(const uint4*)(Bc + d1);
        uint4 b2v = *(const uint4*)(Bc + d2);
        uint4 b3 = *(const uint4*)(Bc + d3);
        uint4 b4 = *(const uint4*)(Bc + d4);
        uint4 b5 = *(const uint4*)(Bc + d5);
        uint4 b6 = *(const uint4*)(Bc + d6);
        uint4 b7 = *(const uint4*)(Bc + d7);
        // keep current pm's before overwriting index regs
        int m0 = q0.y, m1 = q0.w, m2 = q1.y, m3 = q1.w;
        int m4 = q2.y, m5 = q2.w, m6 = q3.y, m7 = q3.w;
        // software pipeline: issue NEXT iteration's index loads before the dots consume gathers
        int sgn = sg + 1;
        if (sgn < s1) {
            sr2 = *(const int2*)&sr[sgn * 2];
            int i0n = sgn * 8;
            q0 = *(const int4*)&pb[i0n];
            q1 = *(const int4*)&pb[i0n + 2];
            q2 = *(const int4*)&pb[i0n + 4];
            q3 = *(const int4*)&pb[i0n + 6];
        }
        float r0 = dot8relu_f16(a0, b0, w2p);
        float r1 = dot8relu_f16(a0, b1, w2p);
        float r2 = dot8relu_f16(a0, b2v, w2p);
        float r3 = dot8relu_f16(a0, b3, w2p);
        float r4 = dot8relu_f16(a1, b4, w2p);
        float r5 = dot8relu_f16(a1, b5, w2p);
        float r6 = dot8relu_f16(a1, b6, w2p);
        float r7 = dot8relu_f16(a1, b7, w2p);
        // merged 8-value butterfly: 9 shuffles for 8 pairs
        float u01 = (l32 & 1) ? r1 : r0, v01 = (l32 & 1) ? r0 : r1;
        u01 += __shfl_xor(v01, 1, 32);
        float u23 = (l32 & 1) ? r3 : r2, v23 = (l32 & 1) ? r2 : r3;
        u23 += __shfl_xor(v23, 1, 32);
        float u45 = (l32 & 1) ? r5 : r4, v45 = (l32 & 1) ? r4 : r5;
        u45 += __shfl_xor(v45, 1, 32);
        float u67 = (l32 & 1) ? r7 : r6, v67 = (l32 & 1) ? r6 : r7;
        u67 += __shfl_xor(v67, 1, 32);
        float w03 = (l32 & 2) ? u23 : u01, wv03 = (l32 & 2) ? u01 : u23;
        w03 += __shfl_xor(wv03, 2, 32);
        float w47 = (l32 & 2) ? u67 : u45, wv47 = (l32 & 2) ? u45 : u67;
        w47 += __shfl_xor(wv47, 2, 32);
        float v = (l32 & 4) ? w47 : w03, vv = (l32 & 4) ? w03 : w47;
        v += __shfl_xor(vv, 4, 32);
        v += __shfl_xor(v, 8, 32);
        v += __shfl_xor(v, 16, 32);
        // lane k (0..7) holds pair k's sum; select its pm
        int pA = (l32 & 1) ? m1 : m0;
        int pB = (l32 & 1) ? m3 : m2;
        int pC = (l32 & 1) ? m5 : m4;
        int pD = (l32 & 1) ? m7 : m6;
        int pAB = (l32 & 2) ? pB : pA;
        int pCD = (l32 & 2) ? pD : pC;
        int p = (l32 & 4) ? pCD : pAB;
        if (l32 < 8 && p >= 0) out[p] = v + b2;
        sg = sgn;
    }
}

extern "C" void kernel_launch(void* const* d_in, const int* in_sizes, int n_in,
                              void* d_out, int out_size, void* d_ws, size_t ws_size,
                              hipStream_t stream) {
    const float* x   = (const float*)d_in[0];
    const int*   ei  = (const int*)d_in[1];
    const float* ew  = (const float*)d_in[2];
    const int*   el  = (const int*)d_in[3];
    const float* Wr1 = (const float*)d_in[4];
    const float* br1 = (const float*)d_in[5];
    const float* Wo1 = (const float*)d_in[6];
    const float* Wr2 = (const float*)d_in[7];
    const float* br2 = (const float*)d_in[8];
    const float* Wo2 = (const float*)d_in[9];
    const float* Wr3 = (const float*)d_in[10];
    const float* br3 = (const float*)d_in[11];
    const float* Wo3 = (const float*)d_in[12];
    const float* Wd1 = (const float*)d_in[13];
    const float* bd1 = (const float*)d_in[14];
    const float* Wd2 = (const float*)d_in[15];
    const float* bd2 = (const float*)d_in[16];
    float* out = (float*)d_out;

    char* ws = (char*)d_ws;
    size_t o = 0;
    auto alloc = [&](size_t bytes) { size_t p = o; o += (bytes + 255) & ~(size_t)255; return (void*)(ws + p); };
    // cnt + pcnt + etot + ptot adjacent -> single zero-memset
    int*     cnt     = (int*)alloc(N_NODES * 4);
    int*     pcnt    = (int*)alloc(NRUNS2 * 4);
    int*     etot    = (int*)alloc(4);
    int*     ptot    = (int*)alloc(8 * 16 * 4);
    size_t   zero_bytes = (size_t)((char*)ptot - (char*)cnt) + 8 * 16 * 4;
    // parr + srun adjacent -> single 0xFF fill (folded into k_fuse1)
    int2*    parr    = (int2*)alloc((size_t)NBUCK * BSEG * 8);
    int*     srun    = (int*)alloc((size_t)NBUCK * (BSEG / 4) * 4);
    int2*    stage   = (int2*)alloc((size_t)64 * PSB * SLOTB * 8);
    int*     scnt    = (int*)alloc((size_t)64 * PSB * 4);
    int2*    csr     = (int2*)alloc((size_t)N_EDGES * 8);
    int*     ebase   = (int*)alloc(N_NODES * 4);
    int*     eend    = (int*)alloc(N_NODES * 4);
    int*     ecur    = (int*)alloc(N_NODES * 4);
    int*     pcur    = (int*)alloc(NRUNS2 * 4);
    // activation buffers (hi always; lo only used for z)
    ushort_t* ash = (ushort_t*)alloc((size_t)N_NODES * 256 * 2);
    ushort_t* asl = (ushort_t*)alloc((size_t)N_NODES * 256 * 2);
    // GEMM outputs: P bf16 (later Atab f16), R fp32 (later Btab f16)
    ushort_t* Pb  = (ushort_t*)alloc((size_t)N_NODES * 256 * 2);
    float*    Rb  = (float*)alloc((size_t)N_NODES * 256 * 4);
    // pre-split transposed weights (hi only)
    ushort_t* r1h = (ushort_t*)alloc(256 * 256 * 2);
    ushort_t* o1h = (ushort_t*)alloc(256 * 256 * 2);
    ushort_t* r2h = (ushort_t*)alloc(128 * 256 * 2);
    ushort_t* o2h = (ushort_t*)alloc(128 * 256 * 2);
    ushort_t* r3h = (ushort_t*)alloc(128 * 128 * 2);
    ushort_t* o3h = (ushort_t*)alloc(128 * 128 * 2);
    ushort_t* dah = (ushort_t*)alloc(256 * 128 * 2);
    ushort_t* dbh = (ushort_t*)alloc(256 * 128 * 2);
    _Float16* Atab = (_Float16*)Pb;
    _Float16* Btab = (_Float16*)Rb;

    hipMemsetAsync(cnt, 0, zero_bytes, stream);

    // K1: pstage (private fixed-slot segments) | edge-hist | xsplit | wsplit | parr/srun 0xFF fill
    k_fuse1<<<7587, 256, 0, stream>>>(el, stage, scnt, ei, cnt, x, ash, (uint4*)parr,
                                      Wr1, Wo1, Wr2, Wo2, Wr3, Wo3, Wd1,
                                      r1h, o1h, r2h, o2h, r3h, o3h, dah, dbh);
    // K2: edge bump-alloc | bucket-local fine histogram
    k_fuse2<<<2088, 256, 0, stream>>>(cnt, ebase, eend, ecur, etot, stage, scnt, pcnt);
    // K3: edge scatter | per-bucket run alloc (+srun)
    k_fuse3<<<1570, 256, 0, stream>>>(ei, ew, ecur, csr, pcnt, pcur, srun, ptot);
    // K4: layer-1 dual GEMM || bucket-local fine scatter
    k_fuse4<<<2676, 256, 0, stream>>>(ash, asl, r1h, o1h, Pb, Rb, stage, scnt, pcur, parr);

    k_aggf<256, true, false><<<2500, 256, 0, stream>>>(Pb, Rb, br1, ebase, eend, csr, ash, asl);

    k_gemm_bf<false, ushort_t, float><<<dim3(GXM, 2), 256, 0, stream>>>(ash, asl, r2h, o2h, nullptr,
                                                                        Pb, Rb, N_NODES, 256, 128);
    k_aggf<128, true, false><<<2500, 256, 0, stream>>>(Pb, Rb, br2, ebase, eend, csr, ash, asl);

    k_gemm_bf<false, ushort_t, float><<<dim3(GXM, 2), 256, 0, stream>>>(ash, asl, r3h, o3h, nullptr,
                                                                        Pb, Rb, N_NODES, 128, 128);
    k_aggf<128, false, true><<<2500, 256, 0, stream>>>(Pb, Rb, br3, ebase, eend, csr, ash, asl);

    // Decoder tables (f16): Atab = z@Wd1_top + bd1, Btab = z@Wd1_bot  (A = z hi/lo)
    k_gemm_bf<true, _Float16, _Float16><<<dim3(GXM, 4), 256, 0, stream>>>(ash, asl, dah, dbh, bd1,
                                                                          Atab, Btab, N_NODES, 128, 256);

    // Decoder (single dispatch, 4096 blocks: backfill TLP + index prefetch)
    k_decoder<<<4096, 256, 0, stream>>>(Atab, Btab, parr, srun, ptot, Wd2, bd2, out);
}

// Round 10
// 296.472 us; speedup vs baseline: 1.2281x; 1.1868x over previous
//
#include <hip/hip_runtime.h>

#define N_NODES 10000
#define N_EDGES 320000
#define N_PAIRS 1000000
#define NBUCK 8
#define DBW 1250            // d-bucket width (N_NODES / 8)
#define SBW 1250            // s-bucket width
#define PSB 512             // pstage producer blocks
#define SLOTB 76            // per (bucket, producer) slot capacity (Poisson(32), P(ovfl)~1e-11); 76 % 4 == 0
#define GXM 157             // (N_NODES + 63) / 64

typedef unsigned short ushort_t;
typedef __attribute__((ext_vector_type(8))) short short8;
typedef __attribute__((ext_vector_type(4))) float floatx4;
typedef _Float16 half2_t __attribute__((ext_vector_type(2)));

__device__ inline float blo(unsigned int u) { return __uint_as_float(u << 16); }
__device__ inline float bhi(unsigned int u) { return __uint_as_float(u & 0xffff0000u); }
__device__ inline ushort_t f2bf(float f) {
    unsigned int u = __float_as_uint(f);
    unsigned int r = (u + 0x7fffu + ((u >> 16) & 1u)) >> 16;
    return (ushort_t)r;
}
__device__ inline float bf2f(ushort_t b) { return __uint_as_float(((unsigned int)b) << 16); }
__device__ inline void stout(float* p, float v) { *p = v; }
__device__ inline void stout(ushort_t* p, float v) { *p = f2bf(v); }
__device__ inline void stout(_Float16* p, float v) { *p = (_Float16)v; }

// ================= device bodies =================

// coarse 64-bucket scatter into PRIVATE fixed-capacity (bucket, block) segments.
// Tail-padded to x4 with (-1,-1) sentinels -> decoder int4 group loads are safe.
__device__ void dev_pstage(int bid, const int* __restrict__ el,
                           int2* __restrict__ stage, int* __restrict__ scnt) {
    __shared__ int lcur[64];
    int t = threadIdx.x;
    if (t < 64) lcur[t] = 0;
    __syncthreads();
    const int STR = PSB * 256;       // 131072; 8 iterations cover 1M
    int i0 = bid * 256 + t;
#pragma unroll
    for (int k = 0; k < 8; k++) {
        int i = i0 + k * STR;
        if (i < N_PAIRS) {
            int s = el[i], d = el[N_PAIRS + i];
            int c = (d / DBW) * 8 + s / SBW;
            int r = atomicAdd(&lcur[c], 1);
            stage[((size_t)c * PSB + bid) * SLOTB + r] = make_int2(s | (d << 14), i);
        }
    }
    __syncthreads();
    if (t < 64) {
        int n = lcur[t];
        scnt[t * PSB + bid] = n;
        int np = (n + 3) & ~3;
        int2* sp = stage + ((size_t)t * PSB + bid) * SLOTB;
        for (int i = n; i < np; ++i) sp[i] = make_int2(-1, -1);
    }
}

__device__ void dev_hist(int bid, const int* __restrict__ ei, int* __restrict__ cnt) {
    int e = bid * 256 + threadIdx.x;
    if (e < N_EDGES) atomicAdd(&cnt[ei[N_EDGES + e]], 1);
}

__device__ void dev_xsplit(int bid, const float* __restrict__ x, ushort_t* __restrict__ xh) {
    int i = bid * 256 + threadIdx.x;
    if (i >= N_NODES * 256 / 4) return;
    float4 f = ((const float4*)x)[i];
    union { uint2 v; ushort_t u[4]; } H;
    H.u[0] = f2bf(f.x); H.u[1] = f2bf(f.y); H.u[2] = f2bf(f.z); H.u[3] = f2bf(f.w);
    ((uint2*)xh)[i] = H.v;
}

__device__ void dev_wsplit(int bx, int by, int bz,
                           const float* Wr1, const float* Wo1, const float* Wr2, const float* Wo2,
                           const float* Wr3, const float* Wo3, const float* Wd1,
                           ushort_t* r1h, ushort_t* o1h, ushort_t* r2h, ushort_t* o2h,
                           ushort_t* r3h, ushort_t* o3h, ushort_t* dah, ushort_t* dbh) {
    const float* src; ushort_t* dh; int K, NC;
    switch (bz) {
        case 0: src = Wr1; dh = r1h; K = 256; NC = 256; break;
        case 1: src = Wo1; dh = o1h; K = 256; NC = 256; break;
        case 2: src = Wr2; dh = r2h; K = 256; NC = 128; break;
        case 3: src = Wo2; dh = o2h; K = 256; NC = 128; break;
        case 4: src = Wr3; dh = r3h; K = 128; NC = 128; break;
        case 5: src = Wo3; dh = o3h; K = 128; NC = 128; break;
        case 6: src = Wd1;             dh = dah; K = 128; NC = 256; break;
        default: src = Wd1 + 128 * 256; dh = dbh; K = 128; NC = 256; break;
    }
    int tk = bx * 32, tn = by * 32;
    if (tk >= K || tn >= NC) return;
    __shared__ float tile[32][33];
    int tx = threadIdx.x & 31, ty0 = threadIdx.x >> 5;
#pragma unroll
    for (int r = 0; r < 4; r++) {
        int k = tk + ty0 + r * 8;
        tile[ty0 + r * 8][tx] = src[(size_t)k * NC + tn + tx];
    }
    __syncthreads();
#pragma unroll
    for (int r = 0; r < 4; r++) {
        int n = tn + ty0 + r * 8;
        dh[(size_t)n * K + tk + tx] = f2bf(tile[tx][ty0 + r * 8]);
    }
}

// block-local scan + one global atomicAdd per block (edges CSR alloc)
__device__ void dev_ealloc(int bid, const int* __restrict__ cnt,
                           int* __restrict__ base_, int* __restrict__ end_,
                           int* __restrict__ cur_, int* __restrict__ tot) {
    __shared__ int part[256];
    __shared__ int bbase;
    int t = threadIdx.x;
    int r = bid * 256 + t;
    int len = (r < N_NODES) ? cnt[r] : 0;
    part[t] = len;
    __syncthreads();
    for (int d = 1; d < 256; d <<= 1) {
        int v = (t >= d) ? part[t - d] : 0;
        __syncthreads();
        part[t] += v;
        __syncthreads();
    }
    if (t == 255) bbase = atomicAdd(tot, part[255]);
    __syncthreads();
    int excl = (t == 0) ? 0 : part[t - 1];
    if (r < N_NODES) {
        int b = bbase + excl;
        base_[r] = b;
        cur_[r] = b;
        end_[r] = b + len;
    }
}

__device__ void dev_scatter(int bid, const int* __restrict__ ei, const float* __restrict__ ew,
                            int* __restrict__ ecur, int2* __restrict__ csr) {
    int e = bid * 256 + threadIdx.x;
    if (e < N_EDGES) {
        int d = ei[N_EDGES + e];
        int pos = atomicAdd(&ecur[d], 1);
        csr[pos] = make_int2(ei[e], __float_as_int(ew[e]));
    }
}

// ---------------- MFMA dual-GEMM body ----------------
template <bool ALO, typename T1, typename T2>
__device__ void dev_gemm(int bx, int by,
                         const ushort_t* __restrict__ Ahi, const ushort_t* __restrict__ Alo,
                         const ushort_t* __restrict__ W1hi, const ushort_t* __restrict__ W2hi,
                         const float* __restrict__ bias1,
                         T1* __restrict__ out1, T2* __restrict__ out2,
                         int M, int K, int NC) {
    __shared__ ushort_t sAh[64][32], sAl[ALO ? 64 : 1][32];
    __shared__ ushort_t s1h[64][32], s2h[64][32];

    int tid = threadIdx.x;
    int lane = tid & 63, wid = tid >> 6;
    int wm = wid >> 1, wn = wid & 1;
    int l15 = lane & 15, quad = lane >> 4;
    int row0 = bx * 64, col0 = by * 64;

    int srow = tid >> 2, schunk = (tid & 3) * 8;
    int arow = row0 + srow; if (arow > M - 1) arow = M - 1;
    const ushort_t* gAh = Ahi + (size_t)arow * K + schunk;
    const ushort_t* gAl = Alo + (size_t)arow * K + schunk;
    int wrow = col0 + srow;
    const ushort_t* g1h = W1hi + (size_t)wrow * K + schunk;
    const ushort_t* g2h = W2hi + (size_t)wrow * K + schunk;

    floatx4 acc1[2][2] = {}, acc2[2][2] = {};

    for (int kk = 0; kk < K; kk += 32) {
        *(short8*)&sAh[srow][schunk] = *(const short8*)(gAh + kk);
        if (ALO) *(short8*)&sAl[srow][schunk] = *(const short8*)(gAl + kk);
        *(short8*)&s1h[srow][schunk] = *(const short8*)(g1h + kk);
        *(short8*)&s2h[srow][schunk] = *(const short8*)(g2h + kk);
        __syncthreads();

        short8 ah[2], al[2], b1h[2], b2h[2];
#pragma unroll
        for (int t = 0; t < 2; t++) {
            int ar = wm * 32 + t * 16 + l15;
            ah[t] = *(const short8*)&sAh[ar][quad * 8];
            if (ALO) al[t] = *(const short8*)&sAl[ar][quad * 8];
            int bc = wn * 32 + t * 16 + l15;
            b1h[t] = *(const short8*)&s1h[bc][quad * 8];
            b2h[t] = *(const short8*)&s2h[bc][quad * 8];
        }
#pragma unroll
        for (int tm = 0; tm < 2; tm++)
#pragma unroll
            for (int tn = 0; tn < 2; tn++) {
                acc1[tm][tn] = __builtin_amdgcn_mfma_f32_16x16x32_bf16(ah[tm], b1h[tn], acc1[tm][tn], 0, 0, 0);
                acc2[tm][tn] = __builtin_amdgcn_mfma_f32_16x16x32_bf16(ah[tm], b2h[tn], acc2[tm][tn], 0, 0, 0);
                if (ALO) {
                    acc1[tm][tn] = __builtin_amdgcn_mfma_f32_16x16x32_bf16(al[tm], b1h[tn], acc1[tm][tn], 0, 0, 0);
                    acc2[tm][tn] = __builtin_amdgcn_mfma_f32_16x16x32_bf16(al[tm], b2h[tn], acc2[tm][tn], 0, 0, 0);
                }
            }
        __syncthreads();
    }

    // C/D layout: col = lane&15, row = quad*4 + reg
#pragma unroll
    for (int tm = 0; tm < 2; tm++) {
#pragma unroll
        for (int tn = 0; tn < 2; tn++) {
            int gc = col0 + wn * 32 + tn * 16 + l15;
            float bv = bias1 ? bias1[gc] : 0.f;
#pragma unroll
            for (int reg = 0; reg < 4; reg++) {
                int gr = row0 + wm * 32 + tm * 16 + quad * 4 + reg;
                if (gr >= M) continue;
                stout(&out1[(size_t)gr * NC + gc], acc1[tm][tn][reg] + bv);
                stout(&out2[(size_t)gr * NC + gc], acc2[tm][tn][reg]);
            }
        }
    }
}

// ================= fused dispatches =================

// K1: [pstage 512 | hist 1250 | xsplit 2500 | wsplit 512] = 4774 blocks
__global__ __launch_bounds__(256) void k_fuse1(
    const int* __restrict__ el, int2* __restrict__ stage, int* __restrict__ scnt,
    const int* __restrict__ ei, int* __restrict__ cnt,
    const float* __restrict__ x, ushort_t* __restrict__ ash,
    const float* Wr1, const float* Wo1, const float* Wr2, const float* Wo2,
    const float* Wr3, const float* Wo3, const float* Wd1,
    ushort_t* r1h, ushort_t* o1h, ushort_t* r2h, ushort_t* o2h,
    ushort_t* r3h, ushort_t* o3h, ushort_t* dah, ushort_t* dbh) {
    int b = blockIdx.x;
    if (b < PSB) { dev_pstage(b, el, stage, scnt); return; }
    b -= PSB;
    if (b < 1250) { dev_hist(b, ei, cnt); return; }
    b -= 1250;
    if (b < 2500) { dev_xsplit(b, x, ash); return; }
    b -= 2500;
    dev_wsplit(b & 7, (b >> 3) & 7, b >> 6, Wr1, Wo1, Wr2, Wo2, Wr3, Wo3, Wd1,
               r1h, o1h, r2h, o2h, r3h, o3h, dah, dbh);
}

// K2: edge CSR alloc (tiny, 40 blocks)
__global__ __launch_bounds__(256) void k_ealloc(const int* __restrict__ cnt,
                                                int* __restrict__ ebase, int* __restrict__ eend,
                                                int* __restrict__ ecur, int* __restrict__ etot) {
    dev_ealloc(blockIdx.x, cnt, ebase, eend, ecur, etot);
}

// K3: [edge scatter 1250 | gemm L1 628] = 1878 blocks -- scatter hides under the layer-1 GEMM
__global__ __launch_bounds__(256) void k_fuse3(
    const int* __restrict__ ei, const float* __restrict__ ew, int* __restrict__ ecur,
    int2* __restrict__ csr,
    const ushort_t* __restrict__ ash, const ushort_t* __restrict__ asl,
    const ushort_t* __restrict__ r1h, const ushort_t* __restrict__ o1h,
    ushort_t* __restrict__ Pb, float* __restrict__ Rb) {
    int b = blockIdx.x;
    if (b < 1250) { dev_scatter(b, ei, ew, ecur, csr); return; }
    b -= 1250;
    dev_gemm<false, ushort_t, float>(b % GXM, b / GXM, ash, asl, r1h, o1h, nullptr,
                                     Pb, Rb, N_NODES, 256, 256);
}

// standalone GEMM wrapper (layers 2, 3, decoder tables)
template <bool ALO, typename T1, typename T2>
__global__ __launch_bounds__(256) void k_gemm_bf(const ushort_t* __restrict__ Ahi, const ushort_t* __restrict__ Alo,
                                                 const ushort_t* __restrict__ W1hi, const ushort_t* __restrict__ W2hi,
                                                 const float* __restrict__ bias1,
                                                 T1* __restrict__ out1, T2* __restrict__ out2,
                                                 int M, int K, int NC) {
    dev_gemm<ALO, T1, T2>(blockIdx.x, blockIdx.y, Ahi, Alo, W1hi, W2hi, bias1, out1, out2, M, K, NC);
}

// ---------------- fused agg epilogue: 4-edge unroll + csr index software-prefetch
// (FP add order identical to the 2-wide loop: acc += (w0*p0 + w1*p1); acc += (w2*p2 + w3*p3)) ----------------
template <int C, bool RELU, bool EMITLO>
__global__ __launch_bounds__(256) void k_aggf(const ushort_t* __restrict__ P, const float* __restrict__ R,
                                              const float* __restrict__ bias,
                                              const int* __restrict__ ebase, const int* __restrict__ eend,
                                              const int2* __restrict__ csr,
                                              ushort_t* __restrict__ hh, ushort_t* __restrict__ hl) {
    int wave = (blockIdx.x * 256 + threadIdx.x) >> 6;
    int lane = threadIdx.x & 63;
    if (wave >= N_NODES) return;
    int beg = ebase[wave], end = eend[wave];
    if constexpr (C == 256) {
        int col = lane * 4;
        float4 acc = {0.f, 0.f, 0.f, 0.f};
        int e = beg;
        int2 p0, p1, p2, p3;
        if (e + 3 < end) { p0 = csr[e]; p1 = csr[e + 1]; p2 = csr[e + 2]; p3 = csr[e + 3]; }
        for (; e + 3 < end; ) {
            float w0 = __int_as_float(p0.y), w1 = __int_as_float(p1.y);
            float w2 = __int_as_float(p2.y), w3 = __int_as_float(p3.y);
            uint2 u0 = *(const uint2*)&P[(size_t)p0.x * 256 + col];
            uint2 u1 = *(const uint2*)&P[(size_t)p1.x * 256 + col];
            uint2 u2 = *(const uint2*)&P[(size_t)p2.x * 256 + col];
            uint2 u3 = *(const uint2*)&P[(size_t)p3.x * 256 + col];
            int en = e + 4;
            if (en + 3 < end) { p0 = csr[en]; p1 = csr[en + 1]; p2 = csr[en + 2]; p3 = csr[en + 3]; }
            acc.x += w0 * blo(u0.x) + w1 * blo(u1.x);
            acc.y += w0 * bhi(u0.x) + w1 * bhi(u1.x);
            acc.z += w0 * blo(u0.y) + w1 * blo(u1.y);
            acc.w += w0 * bhi(u0.y) + w1 * bhi(u1.y);
            acc.x += w2 * blo(u2.x) + w3 * blo(u3.x);
            acc.y += w2 * bhi(u2.x) + w3 * bhi(u3.x);
            acc.z += w2 * blo(u2.y) + w3 * blo(u3.y);
            acc.w += w2 * bhi(u2.y) + w3 * bhi(u3.y);
            e = en;
        }
        for (; e + 1 < end; e += 2) {
            int2 q0 = csr[e], q1 = csr[e + 1];
            float w0 = __int_as_float(q0.y), w1 = __int_as_float(q1.y);
            uint2 u0 = *(const uint2*)&P[(size_t)q0.x * 256 + col];
            uint2 u1 = *(const uint2*)&P[(size_t)q1.x * 256 + col];
            acc.x += w0 * blo(u0.x) + w1 * blo(u1.x);
            acc.y += w0 * bhi(u0.x) + w1 * bhi(u1.x);
            acc.z += w0 * blo(u0.y) + w1 * blo(u1.y);
            acc.w += w0 * bhi(u0.y) + w1 * bhi(u1.y);
        }
        if (e < end) {
            int2 q0 = csr[e];
            float w0 = __int_as_float(q0.y);
            uint2 u0 = *(const uint2*)&P[(size_t)q0.x * 256 + col];
            acc.x += w0 * blo(u0.x); acc.y += w0 * bhi(u0.x);
            acc.z += w0 * blo(u0.y); acc.w += w0 * bhi(u0.y);
        }
        float4 rr = *(const float4*)&R[(size_t)wave * 256 + col];
        float4 bb = *(const float4*)&bias[col];
        float o[4];
        o[0] = acc.x + rr.x + bb.x; o[1] = acc.y + rr.y + bb.y;
        o[2] = acc.z + rr.z + bb.z; o[3] = acc.w + rr.w + bb.w;
        if (RELU) {
#pragma unroll
            for (int j = 0; j < 4; j++) o[j] = fmaxf(o[j], 0.f);
        }
        union { uint2 v; ushort_t u[4]; } H, L;
#pragma unroll
        for (int j = 0; j < 4; j++) {
            ushort_t h = f2bf(o[j]);
            H.u[j] = h;
            if (EMITLO) L.u[j] = f2bf(o[j] - bf2f(h));
        }
        *(uint2*)&hh[(size_t)wave * 256 + col] = H.v;
        if (EMITLO) *(uint2*)&hl[(size_t)wave * 256 + col] = L.v;
    } else {
        int col = lane * 2;
        float2 acc = {0.f, 0.f};
        int e = beg;
        int2 p0, p1, p2, p3;
        if (e + 3 < end) { p0 = csr[e]; p1 = csr[e + 1]; p2 = csr[e + 2]; p3 = csr[e + 3]; }
        for (; e + 3 < end; ) {
            float w0 = __int_as_float(p0.y), w1 = __int_as_float(p1.y);
            float w2 = __int_as_float(p2.y), w3 = __int_as_float(p3.y);
            unsigned int u0 = *(const unsigned int*)&P[(size_t)p0.x * 128 + col];
            unsigned int u1 = *(const unsigned int*)&P[(size_t)p1.x * 128 + col];
            unsigned int u2 = *(const unsigned int*)&P[(size_t)p2.x * 128 + col];
            unsigned int u3 = *(const unsigned int*)&P[(size_t)p3.x * 128 + col];
            int en = e + 4;
            if (en + 3 < end) { p0 = csr[en]; p1 = csr[en + 1]; p2 = csr[en + 2]; p3 = csr[en + 3]; }
            acc.x += w0 * blo(u0) + w1 * blo(u1);
            acc.y += w0 * bhi(u0) + w1 * bhi(u1);
            acc.x += w2 * blo(u2) + w3 * blo(u3);
            acc.y += w2 * bhi(u2) + w3 * bhi(u3);
            e = en;
        }
        for (; e + 1 < end; e += 2) {
            int2 q0 = csr[e], q1 = csr[e + 1];
            float w0 = __int_as_float(q0.y), w1 = __int_as_float(q1.y);
            unsigned int u0 = *(const unsigned int*)&P[(size_t)q0.x * 128 + col];
            unsigned int u1 = *(const unsigned int*)&P[(size_t)q1.x * 128 + col];
            acc.x += w0 * blo(u0) + w1 * blo(u1);
            acc.y += w0 * bhi(u0) + w1 * bhi(u1);
        }
        if (e < end) {
            int2 q0 = csr[e];
            float w0 = __int_as_float(q0.y);
            unsigned int u0 = *(const unsigned int*)&P[(size_t)q0.x * 128 + col];
            acc.x += w0 * blo(u0); acc.y += w0 * bhi(u0);
        }
        float2 rr = *(const float2*)&R[(size_t)wave * 128 + col];
        float2 bb = *(const float2*)&bias[col];
        float o0 = acc.x + rr.x + bb.x, o1 = acc.y + rr.y + bb.y;
        if (RELU) { o0 = fmaxf(o0, 0.f); o1 = fmaxf(o1, 0.f); }
        union { unsigned int v; ushort_t u[2]; } H, L;
        ushort_t h0 = f2bf(o0), h1 = f2bf(o1);
        H.u[0] = h0; H.u[1] = h1;
        *(unsigned int*)&hh[(size_t)wave * 128 + col] = H.v;
        if (EMITLO) {
            L.u[0] = f2bf(o0 - bf2f(h0)); L.u[1] = f2bf(o1 - bf2f(h1));
            *(unsigned int*)&hl[(size_t)wave * 128 + col] = L.v;
        }
    }
}

// ---------------- decoder: segment-direct, A+B both XCD-L2-local, 4 pairs/iter ----------------
// No fine sort: each half-wave consumes one (bucket, producer) segment. s,d each confined
// to a 1250-range -> A-slice (640 KB) + B-slice (640 KB) L2-resident per block slab.
__device__ inline float dot8relu_f16(uint4 ua, uint4 ub, const half2_t* w2p) {
    half2_t z = {(_Float16)0.f, (_Float16)0.f};
    float r = 0.f;
    half2_t s;
    s = __builtin_elementwise_max(__builtin_bit_cast(half2_t, ua.x) + __builtin_bit_cast(half2_t, ub.x), z);
    r = __builtin_amdgcn_fdot2(s, w2p[0], r, false);
    s = __builtin_elementwise_max(__builtin_bit_cast(half2_t, ua.y) + __builtin_bit_cast(half2_t, ub.y), z);
    r = __builtin_amdgcn_fdot2(s, w2p[1], r, false);
    s = __builtin_elementwise_max(__builtin_bit_cast(half2_t, ua.z) + __builtin_bit_cast(half2_t, ub.z), z);
    r = __builtin_amdgcn_fdot2(s, w2p[2], r, false);
    s = __builtin_elementwise_max(__builtin_bit_cast(half2_t, ua.w) + __builtin_bit_cast(half2_t, ub.w), z);
    r = __builtin_amdgcn_fdot2(s, w2p[3], r, false);
    return r;
}

__global__ __launch_bounds__(256) void k_decoder(const _Float16* __restrict__ Ab, const _Float16* __restrict__ Bb,
                                                 const int2* __restrict__ stage, const int* __restrict__ scnt,
                                                 const float* __restrict__ Wd2, const float* __restrict__ bd2,
                                                 float* __restrict__ out) {
    int x = blockIdx.x & 7;            // d-bucket == XCD
    int t = blockIdx.x >> 3;           // [0,512)
    int sb = t >> 6;                   // s-bucket: 64 consecutive blocks share (x,sb) -> L2 slab reuse
    int bi = t & 63;
    int hw = threadIdx.x >> 5;
    int l32 = threadIdx.x & 31;
    int pb = bi * 8 + hw;              // producer segment [0,512)
    int c = x * 8 + sb;
    int n = scnt[c * PSB + pb];
    int ng = (n + 3) >> 2;             // tail sentinel-padded to x4 in pstage
    const int2* sp = stage + ((size_t)c * PSB + pb) * SLOTB;
    int col = l32 * 8;                 // 8 f16 = 16 B per lane
    half2_t w2p[4];
#pragma unroll
    for (int q = 0; q < 4; q++) {
        half2_t w = {(_Float16)Wd2[col + 2 * q], (_Float16)Wd2[col + 2 * q + 1]};
        w2p[q] = w;
    }
    float b2 = bd2[0];
    const char* Ac = (const char*)Ab + (size_t)col * 2;
    const char* Bc = (const char*)Bb + (size_t)col * 2;

    for (int g = 0; g < ng; ++g) {
        int4 q0 = *(const int4*)&sp[g * 4];        // (w0, pm0, w1, pm1)
        int4 q1 = *(const int4*)&sp[g * 4 + 2];    // (w2, pm2, w3, pm3)
        // sentinel w = -1 -> clamp to 0 (row 0 garbage dot; pm = -1 blocks the store)
        int w0 = max(q0.x, 0), w1 = max(q0.z, 0);
        int w2i = max(q1.x, 0), w3 = max(q1.z, 0);
        // w = s | d<<14 ; Atab row byte off = s*512, Btab row byte off = d*512
        uint4 a0 = *(const uint4*)(Ac + ((w0 & 16383) << 9));
        uint4 b0 = *(const uint4*)(Bc + ((w0 >> 14) << 9));
        uint4 a1 = *(const uint4*)(Ac + ((w1 & 16383) << 9));
        uint4 b1 = *(const uint4*)(Bc + ((w1 >> 14) << 9));
        uint4 a2 = *(const uint4*)(Ac + ((w2i & 16383) << 9));
        uint4 b2v = *(const uint4*)(Bc + ((w2i >> 14) << 9));
        uint4 a3 = *(const uint4*)(Ac + ((w3 & 16383) << 9));
        uint4 b3 = *(const uint4*)(Bc + ((w3 >> 14) << 9));
        float r0 = dot8relu_f16(a0, b0, w2p);
        float r1 = dot8relu_f16(a1, b1, w2p);
        float r2 = dot8relu_f16(a2, b2v, w2p);
        float r3 = dot8relu_f16(a3, b3, w2p);
        // merged 4-value butterfly (same add order as rounds 3-9)
        float u01 = (l32 & 1) ? r1 : r0;
        float v01 = (l32 & 1) ? r0 : r1;
        u01 += __shfl_xor(v01, 1, 32);
        float u23 = (l32 & 1) ? r3 : r2;
        float v23 = (l32 & 1) ? r2 : r3;
        u23 += __shfl_xor(v23, 1, 32);
        float w_ = (l32 & 2) ? u23 : u01;
        float wv = (l32 & 2) ? u01 : u23;
        w_ += __shfl_xor(wv, 2, 32);
        w_ += __shfl_xor(w_, 4, 32);
        w_ += __shfl_xor(w_, 8, 32);
        w_ += __shfl_xor(w_, 16, 32);
        if (l32 < 4) {
            int p = (l32 == 0) ? q0.y : (l32 == 1) ? q0.w : (l32 == 2) ? q1.y : q1.w;
            if (p >= 0) out[p] = w_ + b2;
        }
    }
}

extern "C" void kernel_launch(void* const* d_in, const int* in_sizes, int n_in,
                              void* d_out, int out_size, void* d_ws, size_t ws_size,
                              hipStream_t stream) {
    const float* x   = (const float*)d_in[0];
    const int*   ei  = (const int*)d_in[1];
    const float* ew  = (const float*)d_in[2];
    const int*   el  = (const int*)d_in[3];
    const float* Wr1 = (const float*)d_in[4];
    const float* br1 = (const float*)d_in[5];
    const float* Wo1 = (const float*)d_in[6];
    const float* Wr2 = (const float*)d_in[7];
    const float* br2 = (const float*)d_in[8];
    const float* Wo2 = (const float*)d_in[9];
    const float* Wr3 = (const float*)d_in[10];
    const float* br3 = (const float*)d_in[11];
    const float* Wo3 = (const float*)d_in[12];
    const float* Wd1 = (const float*)d_in[13];
    const float* bd1 = (const float*)d_in[14];
    const float* Wd2 = (const float*)d_in[15];
    const float* bd2 = (const float*)d_in[16];
    float* out = (float*)d_out;

    char* ws = (char*)d_ws;
    size_t o = 0;
    auto alloc = [&](size_t bytes) { size_t p = o; o += (bytes + 255) & ~(size_t)255; return (void*)(ws + p); };
    // cnt + etot adjacent -> single small zero-memset
    int*     cnt     = (int*)alloc(N_NODES * 4);
    int*     etot    = (int*)alloc(4);
    size_t   zero_bytes = (size_t)((char*)etot - (char*)cnt) + 256;
    int2*    stage   = (int2*)alloc((size_t)64 * PSB * SLOTB * 8);
    int*     scnt    = (int*)alloc((size_t)64 * PSB * 4);
    int2*    csr     = (int2*)alloc((size_t)N_EDGES * 8);
    int*     ebase   = (int*)alloc(N_NODES * 4);
    int*     eend    = (int*)alloc(N_NODES * 4);
    int*     ecur    = (int*)alloc(N_NODES * 4);
    // activation buffers (hi always; lo only used for z)
    ushort_t* ash = (ushort_t*)alloc((size_t)N_NODES * 256 * 2);
    ushort_t* asl = (ushort_t*)alloc((size_t)N_NODES * 256 * 2);
    // GEMM outputs: P bf16 (later Atab f16), R fp32 (later Btab f16)
    ushort_t* Pb  = (ushort_t*)alloc((size_t)N_NODES * 256 * 2);
    float*    Rb  = (float*)alloc((size_t)N_NODES * 256 * 4);
    // pre-split transposed weights (hi only)
    ushort_t* r1h = (ushort_t*)alloc(256 * 256 * 2);
    ushort_t* o1h = (ushort_t*)alloc(256 * 256 * 2);
    ushort_t* r2h = (ushort_t*)alloc(128 * 256 * 2);
    ushort_t* o2h = (ushort_t*)alloc(128 * 256 * 2);
    ushort_t* r3h = (ushort_t*)alloc(128 * 128 * 2);
    ushort_t* o3h = (ushort_t*)alloc(128 * 128 * 2);
    ushort_t* dah = (ushort_t*)alloc(256 * 128 * 2);
    ushort_t* dbh = (ushort_t*)alloc(256 * 128 * 2);
    _Float16* Atab = (_Float16*)Pb;
    _Float16* Btab = (_Float16*)Rb;

    hipMemsetAsync(cnt, 0, zero_bytes, stream);

    // K1: pstage (private segments, sentinel-padded) | edge-hist | xsplit | wsplit
    k_fuse1<<<4774, 256, 0, stream>>>(el, stage, scnt, ei, cnt, x, ash,
                                      Wr1, Wo1, Wr2, Wo2, Wr3, Wo3, Wd1,
                                      r1h, o1h, r2h, o2h, r3h, o3h, dah, dbh);
    // K2: edge CSR bump-alloc (tiny)
    k_ealloc<<<40, 256, 0, stream>>>(cnt, ebase, eend, ecur, etot);
    // K3: edge scatter || layer-1 dual GEMM
    k_fuse3<<<1878, 256, 0, stream>>>(ei, ew, ecur, csr, ash, asl, r1h, o1h, Pb, Rb);

    k_aggf<256, true, false><<<2500, 256, 0, stream>>>(Pb, Rb, br1, ebase, eend, csr, ash, asl);

    k_gemm_bf<false, ushort_t, float><<<dim3(GXM, 2), 256, 0, stream>>>(ash, asl, r2h, o2h, nullptr,
                                                                        Pb, Rb, N_NODES, 256, 128);
    k_aggf<128, true, false><<<2500, 256, 0, stream>>>(Pb, Rb, br2, ebase, eend, csr, ash, asl);

    k_gemm_bf<false, ushort_t, float><<<dim3(GXM, 2), 256, 0, stream>>>(ash, asl, r3h, o3h, nullptr,
                                                                        Pb, Rb, N_NODES, 128, 128);
    k_aggf<128, false, true><<<2500, 256, 0, stream>>>(Pb, Rb, br3, ebase, eend, csr, ash, asl);

    // Decoder tables (f16): Atab = z@Wd1_top + bd1, Btab = z@Wd1_bot  (A = z hi/lo)
    k_gemm_bf<true, _Float16, _Float16><<<dim3(GXM, 4), 256, 0, stream>>>(ash, asl, dah, dbh, bd1,
                                                                          Atab, Btab, N_NODES, 128, 256);

    // Decoder (segment-direct: no fine sort; A+B gathers both XCD-L2-local)
    k_decoder<<<4096, 256, 0, stream>>>(Atab, Btab, stage, scnt, Wd2, bd2, out);
}

// Round 12
// 295.123 us; speedup vs baseline: 1.2337x; 1.0046x over previous
//
#include <hip/hip_runtime.h>

#define N_NODES 10000
#define N_EDGES 320000
#define N_PAIRS 1000000
#define NBUCK 8
#define DBW 1250            // d-bucket width (N_NODES / 8)
#define SBW 1250            // s-bucket width
#define PSB 512             // pstage producer blocks
#define SLOTB 84            // per (bucket, producer) slot capacity; >= x8-padded Poisson(32) tail
#define GXM 157             // (N_NODES + 63) / 64

typedef unsigned short ushort_t;
typedef __attribute__((ext_vector_type(8))) short short8;
typedef __attribute__((ext_vector_type(4))) float floatx4;
typedef _Float16 half2_t __attribute__((ext_vector_type(2)));

__device__ inline float blo(unsigned int u) { return __uint_as_float(u << 16); }
__device__ inline float bhi(unsigned int u) { return __uint_as_float(u & 0xffff0000u); }
__device__ inline ushort_t f2bf(float f) {
    unsigned int u = __float_as_uint(f);
    unsigned int r = (u + 0x7fffu + ((u >> 16) & 1u)) >> 16;
    return (ushort_t)r;
}
__device__ inline float bf2f(ushort_t b) { return __uint_as_float(((unsigned int)b) << 16); }
__device__ inline void stout(float* p, float v) { *p = v; }
__device__ inline void stout(ushort_t* p, float v) { *p = f2bf(v); }
__device__ inline void stout(_Float16* p, float v) { *p = (_Float16)v; }

// ================= device bodies =================

// coarse 64-bucket scatter into PRIVATE fixed-capacity (bucket, block) segments.
// Tail-padded to x8 with (-1,-1) sentinels -> decoder 8-pair int4 group loads are safe.
__device__ void dev_pstage(int bid, const int* __restrict__ el,
                           int2* __restrict__ stage, int* __restrict__ scnt) {
    __shared__ int lcur[64];
    int t = threadIdx.x;
    if (t < 64) lcur[t] = 0;
    __syncthreads();
    const int STR = PSB * 256;       // 131072; 8 iterations cover 1M
    int i0 = bid * 256 + t;
#pragma unroll
    for (int k = 0; k < 8; k++) {
        int i = i0 + k * STR;
        if (i < N_PAIRS) {
            int s = el[i], d = el[N_PAIRS + i];
            int c = (d / DBW) * 8 + s / SBW;
            int r = atomicAdd(&lcur[c], 1);
            stage[((size_t)c * PSB + bid) * SLOTB + r] = make_int2(s | (d << 14), i);
        }
    }
    __syncthreads();
    if (t < 64) {
        int n = lcur[t];
        scnt[t * PSB + bid] = n;
        int np = (n + 7) & ~7;       // x8 pad (8-pair decoder iterations)
        int2* sp = stage + ((size_t)t * PSB + bid) * SLOTB;
        for (int i = n; i < np; ++i) sp[i] = make_int2(-1, -1);
    }
}

__device__ void dev_hist(int bid, const int* __restrict__ ei, int* __restrict__ cnt) {
    int e = bid * 256 + threadIdx.x;
    if (e < N_EDGES) atomicAdd(&cnt[ei[N_EDGES + e]], 1);
}

__device__ void dev_xsplit(int bid, const float* __restrict__ x, ushort_t* __restrict__ xh) {
    int i = bid * 256 + threadIdx.x;
    if (i >= N_NODES * 256 / 4) return;
    float4 f = ((const float4*)x)[i];
    union { uint2 v; ushort_t u[4]; } H;
    H.u[0] = f2bf(f.x); H.u[1] = f2bf(f.y); H.u[2] = f2bf(f.z); H.u[3] = f2bf(f.w);
    ((uint2*)xh)[i] = H.v;
}

__device__ void dev_wsplit(int bx, int by, int bz,
                           const float* Wr1, const float* Wo1, const float* Wr2, const float* Wo2,
                           const float* Wr3, const float* Wo3, const float* Wd1,
                           ushort_t* r1h, ushort_t* o1h, ushort_t* r2h, ushort_t* o2h,
                           ushort_t* r3h, ushort_t* o3h, ushort_t* dah, ushort_t* dbh) {
    const float* src; ushort_t* dh; int K, NC;
    switch (bz) {
        case 0: src = Wr1; dh = r1h; K = 256; NC = 256; break;
        case 1: src = Wo1; dh = o1h; K = 256; NC = 256; break;
        case 2: src = Wr2; dh = r2h; K = 256; NC = 128; break;
        case 3: src = Wo2; dh = o2h; K = 256; NC = 128; break;
        case 4: src = Wr3; dh = r3h; K = 128; NC = 128; break;
        case 5: src = Wo3; dh = o3h; K = 128; NC = 128; break;
        case 6: src = Wd1;             dh = dah; K = 128; NC = 256; break;
        default: src = Wd1 + 128 * 256; dh = dbh; K = 128; NC = 256; break;
    }
    int tk = bx * 32, tn = by * 32;
    if (tk >= K || tn >= NC) return;
    __shared__ float tile[32][33];
    int tx = threadIdx.x & 31, ty0 = threadIdx.x >> 5;
#pragma unroll
    for (int r = 0; r < 4; r++) {
        int k = tk + ty0 + r * 8;
        tile[ty0 + r * 8][tx] = src[(size_t)k * NC + tn + tx];
    }
    __syncthreads();
#pragma unroll
    for (int r = 0; r < 4; r++) {
        int n = tn + ty0 + r * 8;
        dh[(size_t)n * K + tk + tx] = f2bf(tile[tx][ty0 + r * 8]);
    }
}

// block-local scan + one global atomicAdd per block (edges CSR alloc)
__device__ void dev_ealloc(int bid, const int* __restrict__ cnt,
                           int* __restrict__ base_, int* __restrict__ end_,
                           int* __restrict__ cur_, int* __restrict__ tot) {
    __shared__ int part[256];
    __shared__ int bbase;
    int t = threadIdx.x;
    int r = bid * 256 + t;
    int len = (r < N_NODES) ? cnt[r] : 0;
    part[t] = len;
    __syncthreads();
    for (int d = 1; d < 256; d <<= 1) {
        int v = (t >= d) ? part[t - d] : 0;
        __syncthreads();
        part[t] += v;
        __syncthreads();
    }
    if (t == 255) bbase = atomicAdd(tot, part[255]);
    __syncthreads();
    int excl = (t == 0) ? 0 : part[t - 1];
    if (r < N_NODES) {
        int b = bbase + excl;
        base_[r] = b;
        cur_[r] = b;
        end_[r] = b + len;
    }
}

__device__ void dev_scatter(int bid, const int* __restrict__ ei, const float* __restrict__ ew,
                            int* __restrict__ ecur, int2* __restrict__ csr) {
    int e = bid * 256 + threadIdx.x;
    if (e < N_EDGES) {
        int d = ei[N_EDGES + e];
        int pos = atomicAdd(&ecur[d], 1);
        csr[pos] = make_int2(ei[e], __float_as_int(ew[e]));
    }
}

// ---------------- MFMA dual-GEMM body ----------------
template <bool ALO, typename T1, typename T2>
__device__ void dev_gemm(int bx, int by,
                         const ushort_t* __restrict__ Ahi, const ushort_t* __restrict__ Alo,
                         const ushort_t* __restrict__ W1hi, const ushort_t* __restrict__ W2hi,
                         const float* __restrict__ bias1,
                         T1* __restrict__ out1, T2* __restrict__ out2,
                         int M, int K, int NC) {
    __shared__ ushort_t sAh[64][32], sAl[ALO ? 64 : 1][32];
    __shared__ ushort_t s1h[64][32], s2h[64][32];

    int tid = threadIdx.x;
    int lane = tid & 63, wid = tid >> 6;
    int wm = wid >> 1, wn = wid & 1;
    int l15 = lane & 15, quad = lane >> 4;
    int row0 = bx * 64, col0 = by * 64;

    int srow = tid >> 2, schunk = (tid & 3) * 8;
    int arow = row0 + srow; if (arow > M - 1) arow = M - 1;
    const ushort_t* gAh = Ahi + (size_t)arow * K + schunk;
    const ushort_t* gAl = Alo + (size_t)arow * K + schunk;
    int wrow = col0 + srow;
    const ushort_t* g1h = W1hi + (size_t)wrow * K + schunk;
    const ushort_t* g2h = W2hi + (size_t)wrow * K + schunk;

    floatx4 acc1[2][2] = {}, acc2[2][2] = {};

    for (int kk = 0; kk < K; kk += 32) {
        *(short8*)&sAh[srow][schunk] = *(const short8*)(gAh + kk);
        if (ALO) *(short8*)&sAl[srow][schunk] = *(const short8*)(gAl + kk);
        *(short8*)&s1h[srow][schunk] = *(const short8*)(g1h + kk);
        *(short8*)&s2h[srow][schunk] = *(const short8*)(g2h + kk);
        __syncthreads();

        short8 ah[2], al[2], b1h[2], b2h[2];
#pragma unroll
        for (int t = 0; t < 2; t++) {
            int ar = wm * 32 + t * 16 + l15;
            ah[t] = *(const short8*)&sAh[ar][quad * 8];
            if (ALO) al[t] = *(const short8*)&sAl[ar][quad * 8];
            int bc = wn * 32 + t * 16 + l15;
            b1h[t] = *(const short8*)&s1h[bc][quad * 8];
            b2h[t] = *(const short8*)&s2h[bc][quad * 8];
        }
#pragma unroll
        for (int tm = 0; tm < 2; tm++)
#pragma unroll
            for (int tn = 0; tn < 2; tn++) {
                acc1[tm][tn] = __builtin_amdgcn_mfma_f32_16x16x32_bf16(ah[tm], b1h[tn], acc1[tm][tn], 0, 0, 0);
                acc2[tm][tn] = __builtin_amdgcn_mfma_f32_16x16x32_bf16(ah[tm], b2h[tn], acc2[tm][tn], 0, 0, 0);
                if (ALO) {
                    acc1[tm][tn] = __builtin_amdgcn_mfma_f32_16x16x32_bf16(al[tm], b1h[tn], acc1[tm][tn], 0, 0, 0);
                    acc2[tm][tn] = __builtin_amdgcn_mfma_f32_16x16x32_bf16(al[tm], b2h[tn], acc2[tm][tn], 0, 0, 0);
                }
            }
        __syncthreads();
    }

    // C/D layout: col = lane&15, row = quad*4 + reg
#pragma unroll
    for (int tm = 0; tm < 2; tm++) {
#pragma unroll
        for (int tn = 0; tn < 2; tn++) {
            int gc = col0 + wn * 32 + tn * 16 + l15;
            float bv = bias1 ? bias1[gc] : 0.f;
#pragma unroll
            for (int reg = 0; reg < 4; reg++) {
                int gr = row0 + wm * 32 + tm * 16 + quad * 4 + reg;
                if (gr >= M) continue;
                stout(&out1[(size_t)gr * NC + gc], acc1[tm][tn][reg] + bv);
                stout(&out2[(size_t)gr * NC + gc], acc2[tm][tn][reg]);
            }
        }
    }
}

// ================= fused dispatches =================

// K1: [pstage 512 | hist 1250 | xsplit 2500 | wsplit 512] = 4774 blocks
__global__ __launch_bounds__(256) void k_fuse1(
    const int* __restrict__ el, int2* __restrict__ stage, int* __restrict__ scnt,
    const int* __restrict__ ei, int* __restrict__ cnt,
    const float* __restrict__ x, ushort_t* __restrict__ ash,
    const float* Wr1, const float* Wo1, const float* Wr2, const float* Wo2,
    const float* Wr3, const float* Wo3, const float* Wd1,
    ushort_t* r1h, ushort_t* o1h, ushort_t* r2h, ushort_t* o2h,
    ushort_t* r3h, ushort_t* o3h, ushort_t* dah, ushort_t* dbh) {
    int b = blockIdx.x;
    if (b < PSB) { dev_pstage(b, el, stage, scnt); return; }
    b -= PSB;
    if (b < 1250) { dev_hist(b, ei, cnt); return; }
    b -= 1250;
    if (b < 2500) { dev_xsplit(b, x, ash); return; }
    b -= 2500;
    dev_wsplit(b & 7, (b >> 3) & 7, b >> 6, Wr1, Wo1, Wr2, Wo2, Wr3, Wo3, Wd1,
               r1h, o1h, r2h, o2h, r3h, o3h, dah, dbh);
}

// K2: edge CSR alloc (tiny, 40 blocks)
__global__ __launch_bounds__(256) void k_ealloc(const int* __restrict__ cnt,
                                                int* __restrict__ ebase, int* __restrict__ eend,
                                                int* __restrict__ ecur, int* __restrict__ etot) {
    dev_ealloc(blockIdx.x, cnt, ebase, eend, ecur, etot);
}

// K3: [edge scatter 1250 | gemm L1 628] = 1878 blocks -- scatter hides under the layer-1 GEMM
__global__ __launch_bounds__(256) void k_fuse3(
    const int* __restrict__ ei, const float* __restrict__ ew, int* __restrict__ ecur,
    int2* __restrict__ csr,
    const ushort_t* __restrict__ ash, const ushort_t* __restrict__ asl,
    const ushort_t* __restrict__ r1h, const ushort_t* __restrict__ o1h,
    ushort_t* __restrict__ Pb, float* __restrict__ Rb) {
    int b = blockIdx.x;
    if (b < 1250) { dev_scatter(b, ei, ew, ecur, csr); return; }
    b -= 1250;
    dev_gemm<false, ushort_t, float>(b % GXM, b / GXM, ash, asl, r1h, o1h, nullptr,
                                     Pb, Rb, N_NODES, 256, 256);
}

// standalone GEMM wrapper (layers 2, 3, decoder tables)
template <bool ALO, typename T1, typename T2>
__global__ __launch_bounds__(256) void k_gemm_bf(const ushort_t* __restrict__ Ahi, const ushort_t* __restrict__ Alo,
                                                 const ushort_t* __restrict__ W1hi, const ushort_t* __restrict__ W2hi,
                                                 const float* __restrict__ bias1,
                                                 T1* __restrict__ out1, T2* __restrict__ out2,
                                                 int M, int K, int NC) {
    dev_gemm<ALO, T1, T2>(blockIdx.x, blockIdx.y, Ahi, Alo, W1hi, W2hi, bias1, out1, out2, M, K, NC);
}

// ---------------- fused agg epilogue: 4-edge unroll + csr index software-prefetch
// (FP add order identical to the 2-wide loop: acc += (w0*p0 + w1*p1); acc += (w2*p2 + w3*p3)) ----------------
template <int C, bool RELU, bool EMITLO>
__global__ __launch_bounds__(256) void k_aggf(const ushort_t* __restrict__ P, const float* __restrict__ R,
                                              const float* __restrict__ bias,
                                              const int* __restrict__ ebase, const int* __restrict__ eend,
                                              const int2* __restrict__ csr,
                                              ushort_t* __restrict__ hh, ushort_t* __restrict__ hl) {
    int wave = (blockIdx.x * 256 + threadIdx.x) >> 6;
    int lane = threadIdx.x & 63;
    if (wave >= N_NODES) return;
    int beg = ebase[wave], end = eend[wave];
    if constexpr (C == 256) {
        int col = lane * 4;
        float4 acc = {0.f, 0.f, 0.f, 0.f};
        int e = beg;
        int2 p0, p1, p2, p3;
        if (e + 3 < end) { p0 = csr[e]; p1 = csr[e + 1]; p2 = csr[e + 2]; p3 = csr[e + 3]; }
        for (; e + 3 < end; ) {
            float w0 = __int_as_float(p0.y), w1 = __int_as_float(p1.y);
            float w2 = __int_as_float(p2.y), w3 = __int_as_float(p3.y);
            uint2 u0 = *(const uint2*)&P[(size_t)p0.x * 256 + col];
            uint2 u1 = *(const uint2*)&P[(size_t)p1.x * 256 + col];
            uint2 u2 = *(const uint2*)&P[(size_t)p2.x * 256 + col];
            uint2 u3 = *(const uint2*)&P[(size_t)p3.x * 256 + col];
            int en = e + 4;
            if (en + 3 < end) { p0 = csr[en]; p1 = csr[en + 1]; p2 = csr[en + 2]; p3 = csr[en + 3]; }
            acc.x += w0 * blo(u0.x) + w1 * blo(u1.x);
            acc.y += w0 * bhi(u0.x) + w1 * bhi(u1.x);
            acc.z += w0 * blo(u0.y) + w1 * blo(u1.y);
            acc.w += w0 * bhi(u0.y) + w1 * bhi(u1.y);
            acc.x += w2 * blo(u2.x) + w3 * blo(u3.x);
            acc.y += w2 * bhi(u2.x) + w3 * bhi(u3.x);
            acc.z += w2 * blo(u2.y) + w3 * blo(u3.y);
            acc.w += w2 * bhi(u2.y) + w3 * bhi(u3.y);
            e = en;
        }
        for (; e + 1 < end; e += 2) {
            int2 q0 = csr[e], q1 = csr[e + 1];
            float w0 = __int_as_float(q0.y), w1 = __int_as_float(q1.y);
            uint2 u0 = *(const uint2*)&P[(size_t)q0.x * 256 + col];
            uint2 u1 = *(const uint2*)&P[(size_t)q1.x * 256 + col];
            acc.x += w0 * blo(u0.x) + w1 * blo(u1.x);
            acc.y += w0 * bhi(u0.x) + w1 * bhi(u1.x);
            acc.z += w0 * blo(u0.y) + w1 * blo(u1.y);
            acc.w += w0 * bhi(u0.y) + w1 * bhi(u1.y);
        }
        if (e < end) {
            int2 q0 = csr[e];
            float w0 = __int_as_float(q0.y);
            uint2 u0 = *(const uint2*)&P[(size_t)q0.x * 256 + col];
            acc.x += w0 * blo(u0.x); acc.y += w0 * bhi(u0.x);
            acc.z += w0 * blo(u0.y); acc.w += w0 * bhi(u0.y);
        }
        float4 rr = *(const float4*)&R[(size_t)wave * 256 + col];
        float4 bb = *(const float4*)&bias[col];
        float o[4];
        o[0] = acc.x + rr.x + bb.x; o[1] = acc.y + rr.y + bb.y;
        o[2] = acc.z + rr.z + bb.z; o[3] = acc.w + rr.w + bb.w;
        if (RELU) {
#pragma unroll
            for (int j = 0; j < 4; j++) o[j] = fmaxf(o[j], 0.f);
        }
        union { uint2 v; ushort_t u[4]; } H, L;
#pragma unroll
        for (int j = 0; j < 4; j++) {
            ushort_t h = f2bf(o[j]);
            H.u[j] = h;
            if (EMITLO) L.u[j] = f2bf(o[j] - bf2f(h));
        }
        *(uint2*)&hh[(size_t)wave * 256 + col] = H.v;
        if (EMITLO) *(uint2*)&hl[(size_t)wave * 256 + col] = L.v;
    } else {
        int col = lane * 2;
        float2 acc = {0.f, 0.f};
        int e = beg;
        int2 p0, p1, p2, p3;
        if (e + 3 < end) { p0 = csr[e]; p1 = csr[e + 1]; p2 = csr[e + 2]; p3 = csr[e + 3]; }
        for (; e + 3 < end; ) {
            float w0 = __int_as_float(p0.y), w1 = __int_as_float(p1.y);
            float w2 = __int_as_float(p2.y), w3 = __int_as_float(p3.y);
            unsigned int u0 = *(const unsigned int*)&P[(size_t)p0.x * 128 + col];
            unsigned int u1 = *(const unsigned int*)&P[(size_t)p1.x * 128 + col];
            unsigned int u2 = *(const unsigned int*)&P[(size_t)p2.x * 128 + col];
            unsigned int u3 = *(const unsigned int*)&P[(size_t)p3.x * 128 + col];
            int en = e + 4;
            if (en + 3 < end) { p0 = csr[en]; p1 = csr[en + 1]; p2 = csr[en + 2]; p3 = csr[en + 3]; }
            acc.x += w0 * blo(u0) + w1 * blo(u1);
            acc.y += w0 * bhi(u0) + w1 * bhi(u1);
            acc.x += w2 * blo(u2) + w3 * blo(u3);
            acc.y += w2 * bhi(u2) + w3 * bhi(u3);
            e = en;
        }
        for (; e + 1 < end; e += 2) {
            int2 q0 = csr[e], q1 = csr[e + 1];
            float w0 = __int_as_float(q0.y), w1 = __int_as_float(q1.y);
            unsigned int u0 = *(const unsigned int*)&P[(size_t)q0.x * 128 + col];
            unsigned int u1 = *(const unsigned int*)&P[(size_t)q1.x * 128 + col];
            acc.x += w0 * blo(u0) + w1 * blo(u1);
            acc.y += w0 * bhi(u0) + w1 * bhi(u1);
        }
        if (e < end) {
            int2 q0 = csr[e];
            float w0 = __int_as_float(q0.y);
            unsigned int u0 = *(const unsigned int*)&P[(size_t)q0.x * 128 + col];
            acc.x += w0 * blo(u0); acc.y += w0 * bhi(u0);
        }
        float2 rr = *(const float2*)&R[(size_t)wave * 128 + col];
        float2 bb = *(const float2*)&bias[col];
        float o0 = acc.x + rr.x + bb.x, o1 = acc.y + rr.y + bb.y;
        if (RELU) { o0 = fmaxf(o0, 0.f); o1 = fmaxf(o1, 0.f); }
        union { unsigned int v; ushort_t u[2]; } H, L;
        ushort_t h0 = f2bf(o0), h1 = f2bf(o1);
        H.u[0] = h0; H.u[1] = h1;
        *(unsigned int*)&hh[(size_t)wave * 128 + col] = H.v;
        if (EMITLO) {
            L.u[0] = f2bf(o0 - bf2f(h0)); L.u[1] = f2bf(o1 - bf2f(h1));
            *(unsigned int*)&hl[(size_t)wave * 128 + col] = L.v;
        }
    }
}

// ---------------- decoder: segment-direct, 8 pairs/iter, 16 gathers in flight ----------------
__device__ inline float dot8relu_f16(uint4 ua, uint4 ub, const half2_t* w2p) {
    half2_t z = {(_Float16)0.f, (_Float16)0.f};
    float r = 0.f;
    half2_t s;
    s = __builtin_elementwise_max(__builtin_bit_cast(half2_t, ua.x) + __builtin_bit_cast(half2_t, ub.x), z);
    r = __builtin_amdgcn_fdot2(s, w2p[0], r, false);
    s = __builtin_elementwise_max(__builtin_bit_cast(half2_t, ua.y) + __builtin_bit_cast(half2_t, ub.y), z);
    r = __builtin_amdgcn_fdot2(s, w2p[1], r, false);
    s = __builtin_elementwise_max(__builtin_bit_cast(half2_t, ua.z) + __builtin_bit_cast(half2_t, ub.z), z);
    r = __builtin_amdgcn_fdot2(s, w2p[2], r, false);
    s = __builtin_elementwise_max(__builtin_bit_cast(half2_t, ua.w) + __builtin_bit_cast(half2_t, ub.w), z);
    r = __builtin_amdgcn_fdot2(s, w2p[3], r, false);
    return r;
}

__global__ __launch_bounds__(256) void k_decoder(const _Float16* __restrict__ Ab, const _Float16* __restrict__ Bb,
                                                 const int2* __restrict__ stage, const int* __restrict__ scnt,
                                                 const float* __restrict__ Wd2, const float* __restrict__ bd2,
                                                 float* __restrict__ out) {
    int x = blockIdx.x & 7;            // d-bucket == XCD
    int t = blockIdx.x >> 3;           // [0,512)
    int sb = t >> 6;                   // s-bucket: 64 consecutive blocks share (x,sb) -> L2 slab reuse
    int bi = t & 63;
    int hw = threadIdx.x >> 5;
    int l32 = threadIdx.x & 31;
    int pb = bi * 8 + hw;              // producer segment [0,512)
    int c = x * 8 + sb;
    int n = scnt[c * PSB + pb];
    int ng = (n + 7) >> 3;             // 8-pair iterations; tail sentinel-padded to x8 in pstage
    const int2* sp = stage + ((size_t)c * PSB + pb) * SLOTB;
    int col = l32 * 8;                 // 8 f16 = 16 B per lane
    half2_t w2p[4];
#pragma unroll
    for (int q = 0; q < 4; q++) {
        half2_t w = {(_Float16)Wd2[col + 2 * q], (_Float16)Wd2[col + 2 * q + 1]};
        w2p[q] = w;
    }
    float b2 = bd2[0];
    const char* Ac = (const char*)Ab + (size_t)col * 2;
    const char* Bc = (const char*)Bb + (size_t)col * 2;

    for (int g = 0; g < ng; ++g) {
        int4 q0 = *(const int4*)&sp[g * 8];        // (w0, pm0, w1, pm1)
        int4 q1 = *(const int4*)&sp[g * 8 + 2];
        int4 q2 = *(const int4*)&sp[g * 8 + 4];
        int4 q3 = *(const int4*)&sp[g * 8 + 6];
        // sentinel w = -1 -> clamp to 0 (row 0 garbage dot; pm = -1 blocks the store)
        int w0 = max(q0.x, 0), w1 = max(q0.z, 0);
        int w2i = max(q1.x, 0), w3 = max(q1.z, 0);
        int w4 = max(q2.x, 0), w5 = max(q2.z, 0);
        int w6 = max(q3.x, 0), w7 = max(q3.z, 0);
        // w = s | d<<14 ; Atab row byte off = s*512, Btab row byte off = d*512
        uint4 a0 = *(const uint4*)(Ac + ((w0 & 16383) << 9));   // 16 independent gathers in flight
        uint4 b0 = *(const uint4*)(Bc + ((w0 >> 14) << 9));
        uint4 a1 = *(const uint4*)(Ac + ((w1 & 16383) << 9));
        uint4 b1 = *(const uint4*)(Bc + ((w1 >> 14) << 9));
        uint4 a2 = *(const uint4*)(Ac + ((w2i & 16383) << 9));
        uint4 b2v = *(const uint4*)(Bc + ((w2i >> 14) << 9));
        uint4 a3 = *(const uint4*)(Ac + ((w3 & 16383) << 9));
        uint4 b3 = *(const uint4*)(Bc + ((w3 >> 14) << 9));
        uint4 a4 = *(const uint4*)(Ac + ((w4 & 16383) << 9));
        uint4 b4 = *(const uint4*)(Bc + ((w4 >> 14) << 9));
        uint4 a5 = *(const uint4*)(Ac + ((w5 & 16383) << 9));
        uint4 b5 = *(const uint4*)(Bc + ((w5 >> 14) << 9));
        uint4 a6 = *(const uint4*)(Ac + ((w6 & 16383) << 9));
        uint4 b6 = *(const uint4*)(Bc + ((w6 >> 14) << 9));
        uint4 a7 = *(const uint4*)(Ac + ((w7 & 16383) << 9));
        uint4 b7 = *(const uint4*)(Bc + ((w7 >> 14) << 9));
        float r0 = dot8relu_f16(a0, b0, w2p);
        float r1 = dot8relu_f16(a1, b1, w2p);
        float r2 = dot8relu_f16(a2, b2v, w2p);
        float r3 = dot8relu_f16(a3, b3, w2p);
        float r4 = dot8relu_f16(a4, b4, w2p);
        float r5 = dot8relu_f16(a5, b5, w2p);
        float r6 = dot8relu_f16(a6, b6, w2p);
        float r7 = dot8relu_f16(a7, b7, w2p);
        // merged 8-value butterfly: 9 shuffles for 8 pairs (same add order as 4-value version)
        float u01 = (l32 & 1) ? r1 : r0, v01 = (l32 & 1) ? r0 : r1;
        u01 += __shfl_xor(v01, 1, 32);
        float u23 = (l32 & 1) ? r3 : r2, v23 = (l32 & 1) ? r2 : r3;
        u23 += __shfl_xor(v23, 1, 32);
        float u45 = (l32 & 1) ? r5 : r4, v45 = (l32 & 1) ? r4 : r5;
        u45 += __shfl_xor(v45, 1, 32);
        float u67 = (l32 & 1) ? r7 : r6, v67 = (l32 & 1) ? r6 : r7;
        u67 += __shfl_xor(v67, 1, 32);
        float w03 = (l32 & 2) ? u23 : u01, wv03 = (l32 & 2) ? u01 : u23;
        w03 += __shfl_xor(wv03, 2, 32);
        float w47 = (l32 & 2) ? u67 : u45, wv47 = (l32 & 2) ? u45 : u67;
        w47 += __shfl_xor(wv47, 2, 32);
        float v = (l32 & 4) ? w47 : w03, vv = (l32 & 4) ? w03 : w47;
        v += __shfl_xor(vv, 4, 32);
        v += __shfl_xor(v, 8, 32);
        v += __shfl_xor(v, 16, 32);
        // lane k (0..7) holds pair k's sum; select its pm
        int pA = (l32 & 1) ? q0.w : q0.y;
        int pB = (l32 & 1) ? q1.w : q1.y;
        int pC = (l32 & 1) ? q2.w : q2.y;
        int pD = (l32 & 1) ? q3.w : q3.y;
        int pAB = (l32 & 2) ? pB : pA;
        int pCD = (l32 & 2) ? pD : pC;
        int p = (l32 & 4) ? pCD : pAB;
        if (l32 < 8 && p >= 0) out[p] = v + b2;
    }
}

extern "C" void kernel_launch(void* const* d_in, const int* in_sizes, int n_in,
                              void* d_out, int out_size, void* d_ws, size_t ws_size,
                              hipStream_t stream) {
    const float* x   = (const float*)d_in[0];
    const int*   ei  = (const int*)d_in[1];
    const float* ew  = (const float*)d_in[2];
    const int*   el  = (const int*)d_in[3];
    const float* Wr1 = (const float*)d_in[4];
    const float* br1 = (const float*)d_in[5];
    const float* Wo1 = (const float*)d_in[6];
    const float* Wr2 = (const float*)d_in[7];
    const float* br2 = (const float*)d_in[8];
    const float* Wo2 = (const float*)d_in[9];
    const float* Wr3 = (const float*)d_in[10];
    const float* br3 = (const float*)d_in[11];
    const float* Wo3 = (const float*)d_in[12];
    const float* Wd1 = (const float*)d_in[13];
    const float* bd1 = (const float*)d_in[14];
    const float* Wd2 = (const float*)d_in[15];
    const float* bd2 = (const float*)d_in[16];
    float* out = (float*)d_out;

    char* ws = (char*)d_ws;
    size_t o = 0;
    auto alloc = [&](size_t bytes) { size_t p = o; o += (bytes + 255) & ~(size_t)255; return (void*)(ws + p); };
    // cnt + etot adjacent -> single small zero-memset
    int*     cnt     = (int*)alloc(N_NODES * 4);
    int*     etot    = (int*)alloc(4);
    size_t   zero_bytes = (size_t)((char*)etot - (char*)cnt) + 256;
    int2*    stage   = (int2*)alloc((size_t)64 * PSB * SLOTB * 8);
    int*     scnt    = (int*)alloc((size_t)64 * PSB * 4);
    int2*    csr     = (int2*)alloc((size_t)N_EDGES * 8);
    int*     ebase   = (int*)alloc(N_NODES * 4);
    int*     eend    = (int*)alloc(N_NODES * 4);
    int*     ecur    = (int*)alloc(N_NODES * 4);
    // activation buffers (hi always; lo only used for z)
    ushort_t* ash = (ushort_t*)alloc((size_t)N_NODES * 256 * 2);
    ushort_t* asl = (ushort_t*)alloc((size_t)N_NODES * 256 * 2);
    // GEMM outputs: P bf16 (later Atab f16), R fp32 (later Btab f16)
    ushort_t* Pb  = (ushort_t*)alloc((size_t)N_NODES * 256 * 2);
    float*    Rb  = (float*)alloc((size_t)N_NODES * 256 * 4);
    // pre-split transposed weights (hi only)
    ushort_t* r1h = (ushort_t*)alloc(256 * 256 * 2);
    ushort_t* o1h = (ushort_t*)alloc(256 * 256 * 2);
    ushort_t* r2h = (ushort_t*)alloc(128 * 256 * 2);
    ushort_t* o2h = (ushort_t*)alloc(128 * 256 * 2);
    ushort_t* r3h = (ushort_t*)alloc(128 * 128 * 2);
    ushort_t* o3h = (ushort_t*)alloc(128 * 128 * 2);
    ushort_t* dah = (ushort_t*)alloc(256 * 128 * 2);
    ushort_t* dbh = (ushort_t*)alloc(256 * 128 * 2);
    _Float16* Atab = (_Float16*)Pb;
    _Float16* Btab = (_Float16*)Rb;

    hipMemsetAsync(cnt, 0, zero_bytes, stream);

    // K1: pstage (private segments, x8 sentinel-padded) | edge-hist | xsplit | wsplit
    k_fuse1<<<4774, 256, 0, stream>>>(el, stage, scnt, ei, cnt, x, ash,
                                      Wr1, Wo1, Wr2, Wo2, Wr3, Wo3, Wd1,
                                      r1h, o1h, r2h, o2h, r3h, o3h, dah, dbh);
    // K2: edge CSR bump-alloc (tiny)
    k_ealloc<<<40, 256, 0, stream>>>(cnt, ebase, eend, ecur, etot);
    // K3: edge scatter || layer-1 dual GEMM
    k_fuse3<<<1878, 256, 0, stream>>>(ei, ew, ecur, csr, ash, asl, r1h, o1h, Pb, Rb);

    k_aggf<256, true, false><<<2500, 256, 0, stream>>>(Pb, Rb, br1, ebase, eend, csr, ash, asl);

    k_gemm_bf<false, ushort_t, float><<<dim3(GXM, 2), 256, 0, stream>>>(ash, asl, r2h, o2h, nullptr,
                                                                        Pb, Rb, N_NODES, 256, 128);
    k_aggf<128, true, false><<<2500, 256, 0, stream>>>(Pb, Rb, br2, ebase, eend, csr, ash, asl);

    k_gemm_bf<false, ushort_t, float><<<dim3(GXM, 2), 256, 0, stream>>>(ash, asl, r3h, o3h, nullptr,
                                                                        Pb, Rb, N_NODES, 128, 128);
    k_aggf<128, false, true><<<2500, 256, 0, stream>>>(Pb, Rb, br3, ebase, eend, csr, ash, asl);

    // Decoder tables (f16): Atab = z@Wd1_top + bd1, Btab = z@Wd1_bot  (A = z hi/lo)
    k_gemm_bf<true, _Float16, _Float16><<<dim3(GXM, 4), 256, 0, stream>>>(ash, asl, dah, dbh, bd1,
                                                                          Atab, Btab, N_NODES, 128, 256);

    // Decoder (segment-direct: 8 pairs/iter, 16 gathers in flight, A+B XCD-L2-local)
    k_decoder<<<4096, 256, 0, stream>>>(Atab, Btab, stage, scnt, Wd2, bd2, out);
}

// Round 13
// 294.682 us; speedup vs baseline: 1.2356x; 1.0015x over previous
//
#include <hip/hip_runtime.h>

#define N_NODES 10000
#define N_EDGES 320000
#define N_PAIRS 1000000
#define NBUCK 8
#define DBW 1250            // d-bucket width (N_NODES / 8)
#define SBW 1250            // s-bucket width
#define PSB 512             // pstage producer blocks
#define SLOTB 84            // per (bucket, producer) slot capacity; >= x8-padded Poisson(32) tail
#define GXM 157             // (N_NODES + 63) / 64

typedef unsigned short ushort_t;
typedef __attribute__((ext_vector_type(8))) short short8;
typedef __attribute__((ext_vector_type(4))) float floatx4;
typedef _Float16 half2_t __attribute__((ext_vector_type(2)));

__device__ inline float blo(unsigned int u) { return __uint_as_float(u << 16); }
__device__ inline float bhi(unsigned int u) { return __uint_as_float(u & 0xffff0000u); }
__device__ inline ushort_t f2bf(float f) {
    unsigned int u = __float_as_uint(f);
    unsigned int r = (u + 0x7fffu + ((u >> 16) & 1u)) >> 16;
    return (ushort_t)r;
}
__device__ inline float bf2f(ushort_t b) { return __uint_as_float(((unsigned int)b) << 16); }
__device__ inline void stout(float* p, float v) { *p = v; }
__device__ inline void stout(ushort_t* p, float v) { *p = f2bf(v); }
__device__ inline void stout(_Float16* p, float v) { *p = (_Float16)v; }

// ================= device bodies =================

// coarse 64-bucket scatter into PRIVATE fixed-capacity (bucket, block) segments.
// Tail-padded to x8 with (-1,-1) sentinels -> decoder 8-pair int4 group loads are safe.
__device__ void dev_pstage(int bid, const int* __restrict__ el,
                           int2* __restrict__ stage, int* __restrict__ scnt) {
    __shared__ int lcur[64];
    int t = threadIdx.x;
    if (t < 64) lcur[t] = 0;
    __syncthreads();
    const int STR = PSB * 256;       // 131072; 8 iterations cover 1M
    int i0 = bid * 256 + t;
#pragma unroll
    for (int k = 0; k < 8; k++) {
        int i = i0 + k * STR;
        if (i < N_PAIRS) {
            int s = el[i], d = el[N_PAIRS + i];
            int c = (d / DBW) * 8 + s / SBW;
            int r = atomicAdd(&lcur[c], 1);
            stage[((size_t)c * PSB + bid) * SLOTB + r] = make_int2(s | (d << 14), i);
        }
    }
    __syncthreads();
    if (t < 64) {
        int n = lcur[t];
        scnt[t * PSB + bid] = n;
        int np = (n + 7) & ~7;       // x8 pad (8-pair decoder iterations)
        int2* sp = stage + ((size_t)t * PSB + bid) * SLOTB;
        for (int i = n; i < np; ++i) sp[i] = make_int2(-1, -1);
    }
}

__device__ void dev_hist(int bid, const int* __restrict__ ei, int* __restrict__ cnt) {
    int e = bid * 256 + threadIdx.x;
    if (e < N_EDGES) atomicAdd(&cnt[ei[N_EDGES + e]], 1);
}

__device__ void dev_xsplit(int bid, const float* __restrict__ x, ushort_t* __restrict__ xh) {
    int i = bid * 256 + threadIdx.x;
    if (i >= N_NODES * 256 / 4) return;
    float4 f = ((const float4*)x)[i];
    union { uint2 v; ushort_t u[4]; } H;
    H.u[0] = f2bf(f.x); H.u[1] = f2bf(f.y); H.u[2] = f2bf(f.z); H.u[3] = f2bf(f.w);
    ((uint2*)xh)[i] = H.v;
}

__device__ void dev_wsplit(int bx, int by, int bz,
                           const float* Wr1, const float* Wo1, const float* Wr2, const float* Wo2,
                           const float* Wr3, const float* Wo3, const float* Wd1,
                           ushort_t* r1h, ushort_t* o1h, ushort_t* r2h, ushort_t* o2h,
                           ushort_t* r3h, ushort_t* o3h, ushort_t* dah, ushort_t* dbh) {
    const float* src; ushort_t* dh; int K, NC;
    switch (bz) {
        case 0: src = Wr1; dh = r1h; K = 256; NC = 256; break;
        case 1: src = Wo1; dh = o1h; K = 256; NC = 256; break;
        case 2: src = Wr2; dh = r2h; K = 256; NC = 128; break;
        case 3: src = Wo2; dh = o2h; K = 256; NC = 128; break;
        case 4: src = Wr3; dh = r3h; K = 128; NC = 128; break;
        case 5: src = Wo3; dh = o3h; K = 128; NC = 128; break;
        case 6: src = Wd1;             dh = dah; K = 128; NC = 256; break;
        default: src = Wd1 + 128 * 256; dh = dbh; K = 128; NC = 256; break;
    }
    int tk = bx * 32, tn = by * 32;
    if (tk >= K || tn >= NC) return;
    __shared__ float tile[32][33];
    int tx = threadIdx.x & 31, ty0 = threadIdx.x >> 5;
#pragma unroll
    for (int r = 0; r < 4; r++) {
        int k = tk + ty0 + r * 8;
        tile[ty0 + r * 8][tx] = src[(size_t)k * NC + tn + tx];
    }
    __syncthreads();
#pragma unroll
    for (int r = 0; r < 4; r++) {
        int n = tn + ty0 + r * 8;
        dh[(size_t)n * K + tk + tx] = f2bf(tile[tx][ty0 + r * 8]);
    }
}

// block-local scan + one global atomicAdd per block (edges CSR alloc)
__device__ void dev_ealloc(int bid, const int* __restrict__ cnt,
                           int* __restrict__ base_, int* __restrict__ end_,
                           int* __restrict__ cur_, int* __restrict__ tot) {
    __shared__ int part[256];
    __shared__ int bbase;
    int t = threadIdx.x;
    int r = bid * 256 + t;
    int len = (r < N_NODES) ? cnt[r] : 0;
    part[t] = len;
    __syncthreads();
    for (int d = 1; d < 256; d <<= 1) {
        int v = (t >= d) ? part[t - d] : 0;
        __syncthreads();
        part[t] += v;
        __syncthreads();
    }
    if (t == 255) bbase = atomicAdd(tot, part[255]);
    __syncthreads();
    int excl = (t == 0) ? 0 : part[t - 1];
    if (r < N_NODES) {
        int b = bbase + excl;
        base_[r] = b;
        cur_[r] = b;
        end_[r] = b + len;
    }
}

__device__ void dev_scatter(int bid, const int* __restrict__ ei, const float* __restrict__ ew,
                            int* __restrict__ ecur, int2* __restrict__ csr) {
    int e = bid * 256 + threadIdx.x;
    if (e < N_EDGES) {
        int d = ei[N_EDGES + e];
        int pos = atomicAdd(&ecur[d], 1);
        csr[pos] = make_int2(ei[e], __float_as_int(ew[e]));
    }
}

// ---------------- MFMA dual-GEMM body ----------------
template <bool ALO, typename T1, typename T2>
__device__ void dev_gemm(int bx, int by,
                         const ushort_t* __restrict__ Ahi, const ushort_t* __restrict__ Alo,
                         const ushort_t* __restrict__ W1hi, const ushort_t* __restrict__ W2hi,
                         const float* __restrict__ bias1,
                         T1* __restrict__ out1, T2* __restrict__ out2,
                         int M, int K, int NC) {
    __shared__ ushort_t sAh[64][32], sAl[ALO ? 64 : 1][32];
    __shared__ ushort_t s1h[64][32], s2h[64][32];

    int tid = threadIdx.x;
    int lane = tid & 63, wid = tid >> 6;
    int wm = wid >> 1, wn = wid & 1;
    int l15 = lane & 15, quad = lane >> 4;
    int row0 = bx * 64, col0 = by * 64;

    int srow = tid >> 2, schunk = (tid & 3) * 8;
    int arow = row0 + srow; if (arow > M - 1) arow = M - 1;
    const ushort_t* gAh = Ahi + (size_t)arow * K + schunk;
    const ushort_t* gAl = Alo + (size_t)arow * K + schunk;
    int wrow = col0 + srow;
    const ushort_t* g1h = W1hi + (size_t)wrow * K + schunk;
    const ushort_t* g2h = W2hi + (size_t)wrow * K + schunk;

    floatx4 acc1[2][2] = {}, acc2[2][2] = {};

    for (int kk = 0; kk < K; kk += 32) {
        *(short8*)&sAh[srow][schunk] = *(const short8*)(gAh + kk);
        if (ALO) *(short8*)&sAl[srow][schunk] = *(const short8*)(gAl + kk);
        *(short8*)&s1h[srow][schunk] = *(const short8*)(g1h + kk);
        *(short8*)&s2h[srow][schunk] = *(const short8*)(g2h + kk);
        __syncthreads();

        short8 ah[2], al[2], b1h[2], b2h[2];
#pragma unroll
        for (int t = 0; t < 2; t++) {
            int ar = wm * 32 + t * 16 + l15;
            ah[t] = *(const short8*)&sAh[ar][quad * 8];
            if (ALO) al[t] = *(const short8*)&sAl[ar][quad * 8];
            int bc = wn * 32 + t * 16 + l15;
            b1h[t] = *(const short8*)&s1h[bc][quad * 8];
            b2h[t] = *(const short8*)&s2h[bc][quad * 8];
        }
#pragma unroll
        for (int tm = 0; tm < 2; tm++)
#pragma unroll
            for (int tn = 0; tn < 2; tn++) {
                acc1[tm][tn] = __builtin_amdgcn_mfma_f32_16x16x32_bf16(ah[tm], b1h[tn], acc1[tm][tn], 0, 0, 0);
                acc2[tm][tn] = __builtin_amdgcn_mfma_f32_16x16x32_bf16(ah[tm], b2h[tn], acc2[tm][tn], 0, 0, 0);
                if (ALO) {
                    acc1[tm][tn] = __builtin_amdgcn_mfma_f32_16x16x32_bf16(al[tm], b1h[tn], acc1[tm][tn], 0, 0, 0);
                    acc2[tm][tn] = __builtin_amdgcn_mfma_f32_16x16x32_bf16(al[tm], b2h[tn], acc2[tm][tn], 0, 0, 0);
                }
            }
        __syncthreads();
    }

    // C/D layout: col = lane&15, row = quad*4 + reg
#pragma unroll
    for (int tm = 0; tm < 2; tm++) {
#pragma unroll
        for (int tn = 0; tn < 2; tn++) {
            int gc = col0 + wn * 32 + tn * 16 + l15;
            float bv = bias1 ? bias1[gc] : 0.f;
#pragma unroll
            for (int reg = 0; reg < 4; reg++) {
                int gr = row0 + wm * 32 + tm * 16 + quad * 4 + reg;
                if (gr >= M) continue;
                stout(&out1[(size_t)gr * NC + gc], acc1[tm][tn][reg] + bv);
                stout(&out2[(size_t)gr * NC + gc], acc2[tm][tn][reg]);
            }
        }
    }
}

// ================= fused dispatches =================

// K1: [pstage 512 | hist 1250 | xsplit 2500 | wsplit 512] = 4774 blocks
__global__ __launch_bounds__(256) void k_fuse1(
    const int* __restrict__ el, int2* __restrict__ stage, int* __restrict__ scnt,
    const int* __restrict__ ei, int* __restrict__ cnt,
    const float* __restrict__ x, ushort_t* __restrict__ ash,
    const float* Wr1, const float* Wo1, const float* Wr2, const float* Wo2,
    const float* Wr3, const float* Wo3, const float* Wd1,
    ushort_t* r1h, ushort_t* o1h, ushort_t* r2h, ushort_t* o2h,
    ushort_t* r3h, ushort_t* o3h, ushort_t* dah, ushort_t* dbh) {
    int b = blockIdx.x;
    if (b < PSB) { dev_pstage(b, el, stage, scnt); return; }
    b -= PSB;
    if (b < 1250) { dev_hist(b, ei, cnt); return; }
    b -= 1250;
    if (b < 2500) { dev_xsplit(b, x, ash); return; }
    b -= 2500;
    dev_wsplit(b & 7, (b >> 3) & 7, b >> 6, Wr1, Wo1, Wr2, Wo2, Wr3, Wo3, Wd1,
               r1h, o1h, r2h, o2h, r3h, o3h, dah, dbh);
}

// K2: edge CSR alloc (tiny, 40 blocks)
__global__ __launch_bounds__(256) void k_ealloc(const int* __restrict__ cnt,
                                                int* __restrict__ ebase, int* __restrict__ eend,
                                                int* __restrict__ ecur, int* __restrict__ etot) {
    dev_ealloc(blockIdx.x, cnt, ebase, eend, ecur, etot);
}

// K3: [edge scatter 1250 | gemm L1 628] = 1878 blocks -- scatter hides under the layer-1 GEMM
__global__ __launch_bounds__(256) void k_fuse3(
    const int* __restrict__ ei, const float* __restrict__ ew, int* __restrict__ ecur,
    int2* __restrict__ csr,
    const ushort_t* __restrict__ ash, const ushort_t* __restrict__ asl,
    const ushort_t* __restrict__ r1h, const ushort_t* __restrict__ o1h,
    ushort_t* __restrict__ Pb, float* __restrict__ Rb) {
    int b = blockIdx.x;
    if (b < 1250) { dev_scatter(b, ei, ew, ecur, csr); return; }
    b -= 1250;
    dev_gemm<false, ushort_t, float>(b % GXM, b / GXM, ash, asl, r1h, o1h, nullptr,
                                     Pb, Rb, N_NODES, 256, 256);
}

// standalone GEMM wrapper (layers 2, 3, decoder tables)
template <bool ALO, typename T1, typename T2>
__global__ __launch_bounds__(256) void k_gemm_bf(const ushort_t* __restrict__ Ahi, const ushort_t* __restrict__ Alo,
                                                 const ushort_t* __restrict__ W1hi, const ushort_t* __restrict__ W2hi,
                                                 const float* __restrict__ bias1,
                                                 T1* __restrict__ out1, T2* __restrict__ out2,
                                                 int M, int K, int NC) {
    dev_gemm<ALO, T1, T2>(blockIdx.x, blockIdx.y, Ahi, Alo, W1hi, W2hi, bias1, out1, out2, M, K, NC);
}

// ---------------- fused agg epilogue: 4-edge unroll + csr index software-prefetch
// (FP add order identical to the 2-wide loop: acc += (w0*p0 + w1*p1); acc += (w2*p2 + w3*p3)) ----------------
template <int C, bool RELU, bool EMITLO>
__global__ __launch_bounds__(256) void k_aggf(const ushort_t* __restrict__ P, const float* __restrict__ R,
                                              const float* __restrict__ bias,
                                              const int* __restrict__ ebase, const int* __restrict__ eend,
                                              const int2* __restrict__ csr,
                                              ushort_t* __restrict__ hh, ushort_t* __restrict__ hl) {
    int wave = (blockIdx.x * 256 + threadIdx.x) >> 6;
    int lane = threadIdx.x & 63;
    if (wave >= N_NODES) return;
    int beg = ebase[wave], end = eend[wave];
    if constexpr (C == 256) {
        int col = lane * 4;
        float4 acc = {0.f, 0.f, 0.f, 0.f};
        int e = beg;
        int2 p0, p1, p2, p3;
        if (e + 3 < end) { p0 = csr[e]; p1 = csr[e + 1]; p2 = csr[e + 2]; p3 = csr[e + 3]; }
        for (; e + 3 < end; ) {
            float w0 = __int_as_float(p0.y), w1 = __int_as_float(p1.y);
            float w2 = __int_as_float(p2.y), w3 = __int_as_float(p3.y);
            uint2 u0 = *(const uint2*)&P[(size_t)p0.x * 256 + col];
            uint2 u1 = *(const uint2*)&P[(size_t)p1.x * 256 + col];
            uint2 u2 = *(const uint2*)&P[(size_t)p2.x * 256 + col];
            uint2 u3 = *(const uint2*)&P[(size_t)p3.x * 256 + col];
            int en = e + 4;
            if (en + 3 < end) { p0 = csr[en]; p1 = csr[en + 1]; p2 = csr[en + 2]; p3 = csr[en + 3]; }
            acc.x += w0 * blo(u0.x) + w1 * blo(u1.x);
            acc.y += w0 * bhi(u0.x) + w1 * bhi(u1.x);
            acc.z += w0 * blo(u0.y) + w1 * blo(u1.y);
            acc.w += w0 * bhi(u0.y) + w1 * bhi(u1.y);
            acc.x += w2 * blo(u2.x) + w3 * blo(u3.x);
            acc.y += w2 * bhi(u2.x) + w3 * bhi(u3.x);
            acc.z += w2 * blo(u2.y) + w3 * blo(u3.y);
            acc.w += w2 * bhi(u2.y) + w3 * bhi(u3.y);
            e = en;
        }
        for (; e + 1 < end; e += 2) {
            int2 q0 = csr[e], q1 = csr[e + 1];
            float w0 = __int_as_float(q0.y), w1 = __int_as_float(q1.y);
            uint2 u0 = *(const uint2*)&P[(size_t)q0.x * 256 + col];
            uint2 u1 = *(const uint2*)&P[(size_t)q1.x * 256 + col];
            acc.x += w0 * blo(u0.x) + w1 * blo(u1.x);
            acc.y += w0 * bhi(u0.x) + w1 * bhi(u1.x);
            acc.z += w0 * blo(u0.y) + w1 * blo(u1.y);
            acc.w += w0 * bhi(u0.y) + w1 * bhi(u1.y);
        }
        if (e < end) {
            int2 q0 = csr[e];
            float w0 = __int_as_float(q0.y);
            uint2 u0 = *(const uint2*)&P[(size_t)q0.x * 256 + col];
            acc.x += w0 * blo(u0.x); acc.y += w0 * bhi(u0.x);
            acc.z += w0 * blo(u0.y); acc.w += w0 * bhi(u0.y);
        }
        float4 rr = *(const float4*)&R[(size_t)wave * 256 + col];
        float4 bb = *(const float4*)&bias[col];
        float o[4];
        o[0] = acc.x + rr.x + bb.x; o[1] = acc.y + rr.y + bb.y;
        o[2] = acc.z + rr.z + bb.z; o[3] = acc.w + rr.w + bb.w;
        if (RELU) {
#pragma unroll
            for (int j = 0; j < 4; j++) o[j] = fmaxf(o[j], 0.f);
        }
        union { uint2 v; ushort_t u[4]; } H, L;
#pragma unroll
        for (int j = 0; j < 4; j++) {
            ushort_t h = f2bf(o[j]);
            H.u[j] = h;
            if (EMITLO) L.u[j] = f2bf(o[j] - bf2f(h));
        }
        *(uint2*)&hh[(size_t)wave * 256 + col] = H.v;
        if (EMITLO) *(uint2*)&hl[(size_t)wave * 256 + col] = L.v;
    } else {
        int col = lane * 2;
        float2 acc = {0.f, 0.f};
        int e = beg;
        int2 p0, p1, p2, p3;
        if (e + 3 < end) { p0 = csr[e]; p1 = csr[e + 1]; p2 = csr[e + 2]; p3 = csr[e + 3]; }
        for (; e + 3 < end; ) {
            float w0 = __int_as_float(p0.y), w1 = __int_as_float(p1.y);
            float w2 = __int_as_float(p2.y), w3 = __int_as_float(p3.y);
            unsigned int u0 = *(const unsigned int*)&P[(size_t)p0.x * 128 + col];
            unsigned int u1 = *(const unsigned int*)&P[(size_t)p1.x * 128 + col];
            unsigned int u2 = *(const unsigned int*)&P[(size_t)p2.x * 128 + col];
            unsigned int u3 = *(const unsigned int*)&P[(size_t)p3.x * 128 + col];
            int en = e + 4;
            if (en + 3 < end) { p0 = csr[en]; p1 = csr[en + 1]; p2 = csr[en + 2]; p3 = csr[en + 3]; }
            acc.x += w0 * blo(u0) + w1 * blo(u1);
            acc.y += w0 * bhi(u0) + w1 * bhi(u1);
            acc.x += w2 * blo(u2) + w3 * blo(u3);
            acc.y += w2 * bhi(u2) + w3 * bhi(u3);
            e = en;
        }
        for (; e + 1 < end; e += 2) {
            int2 q0 = csr[e], q1 = csr[e + 1];
            float w0 = __int_as_float(q0.y), w1 = __int_as_float(q1.y);
            unsigned int u0 = *(const unsigned int*)&P[(size_t)q0.x * 128 + col];
            unsigned int u1 = *(const unsigned int*)&P[(size_t)q1.x * 128 + col];
            acc.x += w0 * blo(u0) + w1 * blo(u1);
            acc.y += w0 * bhi(u0) + w1 * bhi(u1);
        }
        if (e < end) {
            int2 q0 = csr[e];
            float w0 = __int_as_float(q0.y);
            unsigned int u0 = *(const unsigned int*)&P[(size_t)q0.x * 128 + col];
            acc.x += w0 * blo(u0); acc.y += w0 * bhi(u0);
        }
        float2 rr = *(const float2*)&R[(size_t)wave * 128 + col];
        float2 bb = *(const float2*)&bias[col];
        float o0 = acc.x + rr.x + bb.x, o1 = acc.y + rr.y + bb.y;
        if (RELU) { o0 = fmaxf(o0, 0.f); o1 = fmaxf(o1, 0.f); }
        union { unsigned int v; ushort_t u[2]; } H, L;
        ushort_t h0 = f2bf(o0), h1 = f2bf(o1);
        H.u[0] = h0; H.u[1] = h1;
        *(unsigned int*)&hh[(size_t)wave * 128 + col] = H.v;
        if (EMITLO) {
            L.u[0] = f2bf(o0 - bf2f(h0)); L.u[1] = f2bf(o1 - bf2f(h1));
            *(unsigned int*)&hl[(size_t)wave * 128 + col] = L.v;
        }
    }
}

// ---------------- decoder: segment-direct, 8 pairs/iter, 16 gathers in flight ----------------
// __launch_bounds__(256, 4): 128-VGPR budget so all 16 gather destinations stay live
// (round-12 build allocated only 32 VGPRs -> compiler serialized the gathers).
__device__ inline float dot8relu_f16(uint4 ua, uint4 ub, const half2_t* w2p) {
    half2_t z = {(_Float16)0.f, (_Float16)0.f};
    float r = 0.f;
    half2_t s;
    s = __builtin_elementwise_max(__builtin_bit_cast(half2_t, ua.x) + __builtin_bit_cast(half2_t, ub.x), z);
    r = __builtin_amdgcn_fdot2(s, w2p[0], r, false);
    s = __builtin_elementwise_max(__builtin_bit_cast(half2_t, ua.y) + __builtin_bit_cast(half2_t, ub.y), z);
    r = __builtin_amdgcn_fdot2(s, w2p[1], r, false);
    s = __builtin_elementwise_max(__builtin_bit_cast(half2_t, ua.z) + __builtin_bit_cast(half2_t, ub.z), z);
    r = __builtin_amdgcn_fdot2(s, w2p[2], r, false);
    s = __builtin_elementwise_max(__builtin_bit_cast(half2_t, ua.w) + __builtin_bit_cast(half2_t, ub.w), z);
    r = __builtin_amdgcn_fdot2(s, w2p[3], r, false);
    return r;
}

__global__ __launch_bounds__(256, 4) void k_decoder(const _Float16* __restrict__ Ab, const _Float16* __restrict__ Bb,
                                                    const int2* __restrict__ stage, const int* __restrict__ scnt,
                                                    const float* __restrict__ Wd2, const float* __restrict__ bd2,
                                                    float* __restrict__ out) {
    int x = blockIdx.x & 7;            // d-bucket == XCD
    int t = blockIdx.x >> 3;           // [0,512)
    int sb = t >> 6;                   // s-bucket: 64 consecutive blocks share (x,sb) -> L2 slab reuse
    int bi = t & 63;
    int hw = threadIdx.x >> 5;
    int l32 = threadIdx.x & 31;
    int pb = bi * 8 + hw;              // producer segment [0,512)
    int c = x * 8 + sb;
    int n = scnt[c * PSB + pb];
    int ng = (n + 7) >> 3;             // 8-pair iterations; tail sentinel-padded to x8 in pstage
    const int2* sp = stage + ((size_t)c * PSB + pb) * SLOTB;
    int col = l32 * 8;                 // 8 f16 = 16 B per lane
    half2_t w2p[4];
#pragma unroll
    for (int q = 0; q < 4; q++) {
        half2_t w = {(_Float16)Wd2[col + 2 * q], (_Float16)Wd2[col + 2 * q + 1]};
        w2p[q] = w;
    }
    float b2 = bd2[0];
    const char* Ac = (const char*)Ab + (size_t)col * 2;
    const char* Bc = (const char*)Bb + (size_t)col * 2;

    for (int g = 0; g < ng; ++g) {
        int4 q0 = *(const int4*)&sp[g * 8];        // (w0, pm0, w1, pm1)
        int4 q1 = *(const int4*)&sp[g * 8 + 2];
        int4 q2 = *(const int4*)&sp[g * 8 + 4];
        int4 q3 = *(const int4*)&sp[g * 8 + 6];
        // sentinel w = -1 -> clamp to 0 (row 0 garbage dot; pm = -1 blocks the store)
        int w0 = max(q0.x, 0), w1 = max(q0.z, 0);
        int w2i = max(q1.x, 0), w3 = max(q1.z, 0);
        int w4 = max(q2.x, 0), w5 = max(q2.z, 0);
        int w6 = max(q3.x, 0), w7 = max(q3.z, 0);
        // w = s | d<<14 ; Atab row byte off = s*512, Btab row byte off = d*512
        uint4 a0 = *(const uint4*)(Ac + ((w0 & 16383) << 9));   // 16 independent gathers in flight
        uint4 b0 = *(const uint4*)(Bc + ((w0 >> 14) << 9));
        uint4 a1 = *(const uint4*)(Ac + ((w1 & 16383) << 9));
        uint4 b1 = *(const uint4*)(Bc + ((w1 >> 14) << 9));
        uint4 a2 = *(const uint4*)(Ac + ((w2i & 16383) << 9));
        uint4 b2v = *(const uint4*)(Bc + ((w2i >> 14) << 9));
        uint4 a3 = *(const uint4*)(Ac + ((w3 & 16383) << 9));
        uint4 b3 = *(const uint4*)(Bc + ((w3 >> 14) << 9));
        uint4 a4 = *(const uint4*)(Ac + ((w4 & 16383) << 9));
        uint4 b4 = *(const uint4*)(Bc + ((w4 >> 14) << 9));
        uint4 a5 = *(const uint4*)(Ac + ((w5 & 16383) << 9));
        uint4 b5 = *(const uint4*)(Bc + ((w5 >> 14) << 9));
        uint4 a6 = *(const uint4*)(Ac + ((w6 & 16383) << 9));
        uint4 b6 = *(const uint4*)(Bc + ((w6 >> 14) << 9));
        uint4 a7 = *(const uint4*)(Ac + ((w7 & 16383) << 9));
        uint4 b7 = *(const uint4*)(Bc + ((w7 >> 14) << 9));
        float r0 = dot8relu_f16(a0, b0, w2p);
        float r1 = dot8relu_f16(a1, b1, w2p);
        float r2 = dot8relu_f16(a2, b2v, w2p);
        float r3 = dot8relu_f16(a3, b3, w2p);
        float r4 = dot8relu_f16(a4, b4, w2p);
        float r5 = dot8relu_f16(a5, b5, w2p);
        float r6 = dot8relu_f16(a6, b6, w2p);
        float r7 = dot8relu_f16(a7, b7, w2p);
        // merged 8-value butterfly: 9 shuffles for 8 pairs (same add order as 4-value version)
        float u01 = (l32 & 1) ? r1 : r0, v01 = (l32 & 1) ? r0 : r1;
        u01 += __shfl_xor(v01, 1, 32);
        float u23 = (l32 & 1) ? r3 : r2, v23 = (l32 & 1) ? r2 : r3;
        u23 += __shfl_xor(v23, 1, 32);
        float u45 = (l32 & 1) ? r5 : r4, v45 = (l32 & 1) ? r4 : r5;
        u45 += __shfl_xor(v45, 1, 32);
        float u67 = (l32 & 1) ? r7 : r6, v67 = (l32 & 1) ? r6 : r7;
        u67 += __shfl_xor(v67, 1, 32);
        float w03 = (l32 & 2) ? u23 : u01, wv03 = (l32 & 2) ? u01 : u23;
        w03 += __shfl_xor(wv03, 2, 32);
        float w47 = (l32 & 2) ? u67 : u45, wv47 = (l32 & 2) ? u45 : u67;
        w47 += __shfl_xor(wv47, 2, 32);
        float v = (l32 & 4) ? w47 : w03, vv = (l32 & 4) ? w03 : w47;
        v += __shfl_xor(vv, 4, 32);
        v += __shfl_xor(v, 8, 32);
        v += __shfl_xor(v, 16, 32);
        // lane k (0..7) holds pair k's sum; select its pm
        int pA = (l32 & 1) ? q0.w : q0.y;
        int pB = (l32 & 1) ? q1.w : q1.y;
        int pC = (l32 & 1) ? q2.w : q2.y;
        int pD = (l32 & 1) ? q3.w : q3.y;
        int pAB = (l32 & 2) ? pB : pA;
        int pCD = (l32 & 2) ? pD : pC;
        int p = (l32 & 4) ? pCD : pAB;
        if (l32 < 8 && p >= 0) out[p] = v + b2;
    }
}

extern "C" void kernel_launch(void* const* d_in, const int* in_sizes, int n_in,
                              void* d_out, int out_size, void* d_ws, size_t ws_size,
                              hipStream_t stream) {
    const float* x   = (const float*)d_in[0];
    const int*   ei  = (const int*)d_in[1];
    const float* ew  = (const float*)d_in[2];
    const int*   el  = (const int*)d_in[3];
    const float* Wr1 = (const float*)d_in[4];
    const float* br1 = (const float*)d_in[5];
    const float* Wo1 = (const float*)d_in[6];
    const float* Wr2 = (const float*)d_in[7];
    const float* br2 = (const float*)d_in[8];
    const float* Wo2 = (const float*)d_in[9];
    const float* Wr3 = (const float*)d_in[10];
    const float* br3 = (const float*)d_in[11];
    const float* Wo3 = (const float*)d_in[12];
    const float* Wd1 = (const float*)d_in[13];
    const float* bd1 = (const float*)d_in[14];
    const float* Wd2 = (const float*)d_in[15];
    const float* bd2 = (const float*)d_in[16];
    float* out = (float*)d_out;

    char* ws = (char*)d_ws;
    size_t o = 0;
    auto alloc = [&](size_t bytes) { size_t p = o; o += (bytes + 255) & ~(size_t)255; return (void*)(ws + p); };
    // cnt + etot adjacent -> single small zero-memset
    int*     cnt     = (int*)alloc(N_NODES * 4);
    int*     etot    = (int*)alloc(4);
    size_t   zero_bytes = (size_t)((char*)etot - (char*)cnt) + 256;
    int2*    stage   = (int2*)alloc((size_t)64 * PSB * SLOTB * 8);
    int*     scnt    = (int*)alloc((size_t)64 * PSB * 4);
    int2*    csr     = (int2*)alloc((size_t)N_EDGES * 8);
    int*     ebase   = (int*)alloc(N_NODES * 4);
    int*     eend    = (int*)alloc(N_NODES * 4);
    int*     ecur    = (int*)alloc(N_NODES * 4);
    // activation buffers (hi always; lo only used for z)
    ushort_t* ash = (ushort_t*)alloc((size_t)N_NODES * 256 * 2);
    ushort_t* asl = (ushort_t*)alloc((size_t)N_NODES * 256 * 2);
    // GEMM outputs: P bf16 (later Atab f16), R fp32 (later Btab f16)
    ushort_t* Pb  = (ushort_t*)alloc((size_t)N_NODES * 256 * 2);
    float*    Rb  = (float*)alloc((size_t)N_NODES * 256 * 4);
    // pre-split transposed weights (hi only)
    ushort_t* r1h = (ushort_t*)alloc(256 * 256 * 2);
    ushort_t* o1h = (ushort_t*)alloc(256 * 256 * 2);
    ushort_t* r2h = (ushort_t*)alloc(128 * 256 * 2);
    ushort_t* o2h = (ushort_t*)alloc(128 * 256 * 2);
    ushort_t* r3h = (ushort_t*)alloc(128 * 128 * 2);
    ushort_t* o3h = (ushort_t*)alloc(128 * 128 * 2);
    ushort_t* dah = (ushort_t*)alloc(256 * 128 * 2);
    ushort_t* dbh = (ushort_t*)alloc(256 * 128 * 2);
    _Float16* Atab = (_Float16*)Pb;
    _Float16* Btab = (_Float16*)Rb;

    hipMemsetAsync(cnt, 0, zero_bytes, stream);

    // K1: pstage (private segments, x8 sentinel-padded) | edge-hist | xsplit | wsplit
    k_fuse1<<<4774, 256, 0, stream>>>(el, stage, scnt, ei, cnt, x, ash,
                                      Wr1, Wo1, Wr2, Wo2, Wr3, Wo3, Wd1,
                                      r1h, o1h, r2h, o2h, r3h, o3h, dah, dbh);
    // K2: edge CSR bump-alloc (tiny)
    k_ealloc<<<40, 256, 0, stream>>>(cnt, ebase, eend, ecur, etot);
    // K3: edge scatter || layer-1 dual GEMM
    k_fuse3<<<1878, 256, 0, stream>>>(ei, ew, ecur, csr, ash, asl, r1h, o1h, Pb, Rb);

    k_aggf<256, true, false><<<2500, 256, 0, stream>>>(Pb, Rb, br1, ebase, eend, csr, ash, asl);

    k_gemm_bf<false, ushort_t, float><<<dim3(GXM, 2), 256, 0, stream>>>(ash, asl, r2h, o2h, nullptr,
                                                                        Pb, Rb, N_NODES, 256, 128);
    k_aggf<128, true, false><<<2500, 256, 0, stream>>>(Pb, Rb, br2, ebase, eend, csr, ash, asl);

    k_gemm_bf<false, ushort_t, float><<<dim3(GXM, 2), 256, 0, stream>>>(ash, asl, r3h, o3h, nullptr,
                                                                        Pb, Rb, N_NODES, 128, 128);
    k_aggf<128, false, true><<<2500, 256, 0, stream>>>(Pb, Rb, br3, ebase, eend, csr, ash, asl);

    // Decoder tables (f16): Atab = z@Wd1_top + bd1, Btab = z@Wd1_bot  (A = z hi/lo)
    k_gemm_bf<true, _Float16, _Float16><<<dim3(GXM, 4), 256, 0, stream>>>(ash, asl, dah, dbh, bd1,
                                                                          Atab, Btab, N_NODES, 128, 256);

    // Decoder (segment-direct: 8 pairs/iter, 128-VGPR budget -> gathers actually overlap)
    k_decoder<<<4096, 256, 0, stream>>>(Atab, Btab, stage, scnt, Wd2, bd2, out);
}